// Round 4
// baseline (718.041 us; speedup 1.0000x reference)
//
#include <hip/hip_runtime.h>
#include <hip/hip_bf16.h>
#include <cstdint>

#define NB    8
#define NPTS  4096
#define NQ    4              // col-quarters -> candidate lists per row
#define PH_COLS 64           // cols per gram phase
#define NPH  (NPTS / PH_COLS)
#define SLOTS 7              // defer-buffer slots/thread (odd -> 2-way LDS banks)
#define SCST  65             // score-tile row stride (65: bank = (r+col)%32, conflict-free)

typedef __attribute__((ext_vector_type(8))) short bf16x8;
typedef __attribute__((ext_vector_type(4))) float f32x4;

// ---------------------------------------------------------------------------
// insert r,m into sorted-descending top-N (D[0] = worst). Caller checks r<D[0].
// ---------------------------------------------------------------------------
template <int N>
__device__ __forceinline__ void insertN(float (&D)[N], int (&M)[N], float r, int m) {
  bool c[N];
#pragma unroll
  for (int i = 0; i < N; ++i) c[i] = (D[i] > r);
#pragma unroll
  for (int i = 0; i < N; ++i) {
    bool  cn = (i < N - 1) ? c[i + 1] : false;
    float dn = (i < N - 1) ? D[i + 1] : 0.f;
    int   mn = (i < N - 1) ? M[i + 1] : 0;
    D[i] = cn ? dn : (c[i] ? r : D[i]);
    M[i] = cn ? mn : (c[i] ? m : M[i]);
  }
}

// ---------------------------------------------------------------------------
// A: x [B,C,N] -> XT fp32 [B,N,64], XH/XL bf16 split [B,N,64], sq[b,n]
// ---------------------------------------------------------------------------
__global__ __launch_bounds__(256) void k_prep(const float* __restrict__ x,
                                              float* __restrict__ xt,
                                              __hip_bfloat16* __restrict__ xh,
                                              __hip_bfloat16* __restrict__ xl,
                                              float* __restrict__ sq) {
  __shared__ float tile[64][65];
  const int b  = blockIdx.y;
  const int n0 = blockIdx.x * 64;
  const int t  = threadIdx.x;
#pragma unroll
  for (int i = 0; i < 16; ++i) {
    int lin = i * 256 + t;
    int c = lin >> 6, j = lin & 63;
    tile[j][c] = x[(size_t)b * 64 * NPTS + (size_t)c * NPTS + n0 + j];
  }
  __syncthreads();
#pragma unroll
  for (int i = 0; i < 16; ++i) {
    int lin = i * 256 + t;
    int j = lin >> 6, c = lin & 63;
    float v = tile[j][c];
    size_t o = ((size_t)b * NPTS + n0 + j) * 64 + c;
    xt[o] = v;
    __hip_bfloat16 h = __float2bfloat16(v);
    xh[o] = h;
    xl[o] = __float2bfloat16(v - __bfloat162float(h));
  }
  if (t < 64) {
    float s = 0.f;
#pragma unroll
    for (int c = 0; c < 64; ++c) { float v = tile[t][c]; s = fmaf(v, v, s); }
    sq[b * NPTS + t + n0] = s;
  }
}

// ---------------------------------------------------------------------------
// B: MFMA Gram + fused approx top-16 per (row, col-quarter).
// Block: 128 rows x all 4096 cols; 512 threads (8 waves, wave w = row-tile w).
// Split-bf16: dot ~= hh + hl + lh (lo*lo dropped; key error ~1.5e-4).
// acc init = -0.5*sq[col]; score = -2*acc = sq[col] - 2*dot  (rank key).
// Phase: MFMA 128x64 tile -> LDS (stride 65), sync, threshold-scan w/ LDS
// defer buffer + wave-voted flush, sync.
// ---------------------------------------------------------------------------
__global__ __launch_bounds__(512, 4) void k_gram(const __hip_bfloat16* __restrict__ xh,
                                                 const __hip_bfloat16* __restrict__ xl,
                                                 const float* __restrict__ sq,
                                                 float* __restrict__ part_d,
                                                 short* __restrict__ part_m) {
  __shared__ float sc[128 * SCST];        // 33280 B
  __shared__ float sqc[2][PH_COLS];
  __shared__ float bufr[512 * SLOTS];     // 14336 B
  __shared__ int   bufm[512 * SLOTS];     // 14336 B

  const int tid  = threadIdx.x;
  const int w    = tid >> 6;
  const int lane = tid & 63;
  const int quad = lane >> 4, l15 = lane & 15;
  const int rb   = blockIdx.x;            // 0..31 row-block
  const int b    = blockIdx.y;            // 0..7
  const size_t xbase = (size_t)b * NPTS * 64;

  // A-fragments (persistent): rows rb*128 + w*16 + l15, k = quad*8..+7 (+32)
  // A layout: A[m=lane&15][k=quad*8+j]  (m120-verified)
  const __hip_bfloat16* ah = xh + xbase + (size_t)(rb * 128 + w * 16 + l15) * 64 + quad * 8;
  const __hip_bfloat16* al = xl + xbase + (size_t)(rb * 128 + w * 16 + l15) * 64 + quad * 8;
  bf16x8 a_h0 = *(const bf16x8*)(ah);
  bf16x8 a_h1 = *(const bf16x8*)(ah + 32);
  bf16x8 a_l0 = *(const bf16x8*)(al);
  bf16x8 a_l1 = *(const bf16x8*)(al + 32);

  // selection state: thread owns (row r, quarter q)
  const int r = tid & 127, q = tid >> 7;
  const int nself = rb * 128 + r;         // self col index within batch
  float D[16]; int M[16];
#pragma unroll
  for (int i = 0; i < 16; ++i) { D[i] = 1e30f; M[i] = 0; }
  int cnt = 0;

  if (tid < PH_COLS) sqc[0][tid] = sq[b * NPTS + tid];
  __syncthreads();

#pragma unroll 1
  for (int p = 0; p < NPH; ++p) {
    const int m0 = p * PH_COLS;
    // prefetch next phase's sq slice
    if (tid < PH_COLS && p + 1 < NPH)
      sqc[(p + 1) & 1][tid] = sq[b * NPTS + m0 + PH_COLS + tid];
    // ---- MFMA phase: 4 col-tiles of 16 ----
#pragma unroll
    for (int ct = 0; ct < 4; ++ct) {
      const __hip_bfloat16* bh = xh + xbase + (size_t)(m0 + ct * 16 + l15) * 64 + quad * 8;
      const __hip_bfloat16* bl = xl + xbase + (size_t)(m0 + ct * 16 + l15) * 64 + quad * 8;
      bf16x8 b_h0 = *(const bf16x8*)(bh);
      bf16x8 b_h1 = *(const bf16x8*)(bh + 32);
      bf16x8 b_l0 = *(const bf16x8*)(bl);
      bf16x8 b_l1 = *(const bf16x8*)(bl + 32);
      float sv = sqc[p & 1][ct * 16 + l15];   // col = lane&15 (C-layout col)
      f32x4 acc = { -0.5f * sv, -0.5f * sv, -0.5f * sv, -0.5f * sv };
      acc = __builtin_amdgcn_mfma_f32_16x16x32_bf16(a_h0, b_h0, acc, 0, 0, 0);
      acc = __builtin_amdgcn_mfma_f32_16x16x32_bf16(a_h1, b_h1, acc, 0, 0, 0);
      acc = __builtin_amdgcn_mfma_f32_16x16x32_bf16(a_h0, b_l0, acc, 0, 0, 0);
      acc = __builtin_amdgcn_mfma_f32_16x16x32_bf16(a_h1, b_l1, acc, 0, 0, 0);
      acc = __builtin_amdgcn_mfma_f32_16x16x32_bf16(a_l0, b_h0, acc, 0, 0, 0);
      acc = __builtin_amdgcn_mfma_f32_16x16x32_bf16(a_l1, b_h1, acc, 0, 0, 0);
      // C layout: col = lane&15, row = quad*4 + reg (m89-verified)
      const int rbase = w * 16 + quad * 4;
      const int colw  = ct * 16 + l15;
#pragma unroll
      for (int i = 0; i < 4; ++i)
        sc[(rbase + i) * SCST + colw] = -2.f * acc[i];
    }
    __syncthreads();
    // ---- scan phase: thread scans 16 cols of its row ----
    const int cb = q * 16;
#pragma unroll 1
    for (int j = 0; j < 16; ++j) {
      float s    = sc[r * SCST + cb + j];
      int   mcol = m0 + cb + j;
      bool pass = (s < D[0]) & (mcol != nself);
      if (pass) { bufr[tid * SLOTS + cnt] = s; bufm[tid * SLOTS + cnt] = mcol; cnt++; }
      if (__any(cnt >= SLOTS - 1)) {
#pragma unroll 1
        for (int i = 0; i < SLOTS; ++i) {
          if (__ballot(i < cnt) == 0ull) break;
          if (i < cnt) {
            float rr = bufr[tid * SLOTS + i];
            int   mm = bufm[tid * SLOTS + i];
            if (rr < D[0]) insertN<16>(D, M, rr, mm);
          }
        }
        cnt = 0;
      }
    }
    __syncthreads();
  }
  // final flush
#pragma unroll 1
  for (int i = 0; i < SLOTS; ++i) {
    if (__ballot(i < cnt) == 0ull) break;
    if (i < cnt) {
      float rr = bufr[tid * SLOTS + i];
      int   mm = bufm[tid * SLOTS + i];
      if (rr < D[0]) insertN<16>(D, M, rr, mm);
    }
  }
  const size_t base = (((size_t)(b * NPTS + nself)) * NQ + q) * 16;
#pragma unroll
  for (int i = 0; i < 16; ++i) {
    part_d[base + i] = D[i];
    part_m[base + i] = (short)M[i];
  }
}

// ---------------------------------------------------------------------------
// C: merge 4 quarter-lists -> approx top-20 candidate indices per row
// ---------------------------------------------------------------------------
__global__ __launch_bounds__(256) void k_merge(const float* __restrict__ part_d,
                                               const short* __restrict__ part_m,
                                               int* __restrict__ cand) {
  const int row = blockIdx.x * 256 + threadIdx.x;   // 0..32767
  float D[20]; int M[20];
#pragma unroll
  for (int i = 0; i < 20; ++i) { D[i] = 1e30f; M[i] = 0; }
#pragma unroll 1
  for (int s = 0; s < NQ; ++s) {
#pragma unroll 1
    for (int i = 0; i < 16; ++i) {
      float rr = part_d[((size_t)row * NQ + s) * 16 + i];
      int   mm = part_m[((size_t)row * NQ + s) * 16 + i];
      if (rr < D[0]) insertN<20>(D, M, rr, mm);
    }
  }
#pragma unroll
  for (int i = 0; i < 20; ++i) cand[(size_t)row * 20 + i] = M[i];
}

// ---------------------------------------------------------------------------
// D: exact fp32 rerank of 20 candidates -> final 16 knn indices (order-free:
// downstream is max-pool). Wave per row; lane = channel; shfl-butterfly dot.
// ---------------------------------------------------------------------------
__global__ __launch_bounds__(256) void k_rerank(const float* __restrict__ xt,
                                                const float* __restrict__ sq,
                                                const int* __restrict__ cand,
                                                int* __restrict__ knn) {
  const int w    = threadIdx.x >> 6;
  const int lane = threadIdx.x & 63;
  const int row  = blockIdx.x * 4 + w;          // 0..32767
  const int b    = row >> 12;
  const float* xb = xt + (size_t)b * NPTS * 64;
  const float cen = xt[(size_t)row * 64 + lane];
  const int mc = cand[(size_t)row * 20 + (lane < 20 ? lane : 0)];
  float rall[20]; int mall[20];
#pragma unroll
  for (int c = 0; c < 20; ++c) {
    int m = __shfl(mc, c);
    float v = cen * xb[(size_t)m * 64 + lane];
#pragma unroll
    for (int off = 32; off; off >>= 1) v += __shfl_xor(v, off);
    rall[c] = sq[b * NPTS + m] - 2.f * v;   // exact fp32 rank key
    mall[c] = m;
  }
  if (lane < 20) {
    float my = rall[lane]; int mym = mall[lane];
    int rk = 0;
#pragma unroll
    for (int j = 0; j < 20; ++j)
      rk += (rall[j] < my) || ((rall[j] == my) && (mall[j] < mym));
    if (rk < 16) knn[(size_t)row * 16 + rk] = mall[lane];
  }
}

// ---------------------------------------------------------------------------
// E: P[n][o] = W1[o]·xt[n] ;  Q[n][o] = (W2-W1)[o]·xt[n] + b1[o] + b2[o]
// ---------------------------------------------------------------------------
__global__ __launch_bounds__(256, 4) void k_pq(const float* __restrict__ xt,
                                               const float* __restrict__ W1,
                                               const float* __restrict__ b1,
                                               const float* __restrict__ W2,
                                               const float* __restrict__ b2,
                                               float* __restrict__ P,
                                               float* __restrict__ Q) {
  const int gn = blockIdx.x * 256 + threadIdx.x;
  const int o0 = blockIdx.y * 16;
  float cen[64];
  {
    const float4* s4 = (const float4*)(xt + (size_t)gn * 64);
    float4* c4 = (float4*)cen;
#pragma unroll
    for (int i = 0; i < 16; ++i) c4[i] = s4[i];
  }
#pragma unroll 1
  for (int oi = 0; oi < 16; ++oi) {
    const int o = o0 + oi;
    float p = 0.f, q2 = 0.f;
#pragma unroll
    for (int c = 0; c < 64; ++c) {
      p  = fmaf(W1[o * 64 + c], cen[c], p);
      q2 = fmaf(W2[o * 64 + c], cen[c], q2);
    }
    P[(size_t)gn * 64 + o] = p;
    Q[(size_t)gn * 64 + o] = q2 - p + b1[o] + b2[o];
  }
}

// ---------------------------------------------------------------------------
// F: y[n][o] = relu(max_k (Q[n][o] + P[knn[n][k]][o]))
// ---------------------------------------------------------------------------
__global__ __launch_bounds__(256) void k_out(const float* __restrict__ P,
                                             const float* __restrict__ Q,
                                             const int* __restrict__ knn,
                                             float* __restrict__ out) {
  __shared__ float tile[64][65];
  const int b    = blockIdx.y;
  const int n0   = blockIdx.x * 64;
  const int wave = threadIdx.x >> 6;
  const int lane = threadIdx.x & 63;
  for (int i = 0; i < 16; ++i) {
    const int nl = wave * 16 + i;
    const int gn = b * NPTS + n0 + nl;
    float acc = -1e30f;
    const float qv = Q[(size_t)gn * 64 + lane];
    const int* id = knn + (size_t)gn * 16;
#pragma unroll
    for (int k = 0; k < 16; ++k) {
      int m = id[k];
      float p = P[((size_t)b * NPTS + m) * 64 + lane];
      acc = fmaxf(acc, qv + p);
    }
    tile[nl][lane] = fmaxf(acc, 0.f);
  }
  __syncthreads();
#pragma unroll
  for (int i = 0; i < 16; ++i) {
    const int o = i * 4 + wave;
    out[((size_t)b * 64 + o) * NPTS + n0 + lane] = tile[lane][o];
  }
}

// ---------------------------------------------------------------------------
extern "C" void kernel_launch(void* const* d_in, const int* in_sizes, int n_in,
                              void* d_out, int out_size, void* d_ws, size_t ws_size,
                              hipStream_t stream) {
  const float* x  = (const float*)d_in[0];
  const float* W1 = (const float*)d_in[1];
  const float* b1 = (const float*)d_in[2];
  const float* W2 = (const float*)d_in[3];
  const float* b2 = (const float*)d_in[4];
  float* out = (float*)d_out;

  // workspace carve-up (~32.6 MB; previous rounds proved >=34 MB available)
  float* ws = (float*)d_ws;
  const size_t NPT_ALL = (size_t)NB * NPTS;               // 32768
  float*          XT    = ws;                             // 2,097,152 f
  float*          SQ    = XT + NPT_ALL * 64;              //    32,768 f
  __hip_bfloat16* XH    = (__hip_bfloat16*)(SQ + NPT_ALL);// 2,097,152 bf16
  __hip_bfloat16* XL    = XH + NPT_ALL * 64;              // 2,097,152 bf16
  float*          PARTD = (float*)(XL + NPT_ALL * 64);    // 2,097,152 f
  short*          PARTM = (short*)(PARTD + NPT_ALL * NQ * 16);
  int*            CAND  = (int*)(PARTM + NPT_ALL * NQ * 16);  // 655,360 i
  int*            KNN   = CAND + NPT_ALL * 20;            // 524,288 i
  float*          Pm    = PARTD;        // overlay: partials dead after merge
  float*          Qm    = (float*)XH;   // overlay: XH/XL dead after gram

  k_prep  <<<dim3(NPTS / 64, NB), 256, 0, stream>>>(x, XT, XH, XL, SQ);
  k_gram  <<<dim3(NPTS / 128, NB), 512, 0, stream>>>(XH, XL, SQ, PARTD, PARTM);
  k_merge <<<dim3(NPT_ALL / 256), 256, 0, stream>>>(PARTD, PARTM, CAND);
  k_rerank<<<dim3(NPT_ALL / 4), 256, 0, stream>>>(XT, SQ, CAND, KNN);
  k_pq    <<<dim3(NPT_ALL / 256, 4), 256, 0, stream>>>(XT, W1, b1, W2, b2, Pm, Qm);
  k_out   <<<dim3(NPTS / 64, NB), 256, 0, stream>>>(Pm, Qm, KNN, out);
}

// Round 5
// 523.164 us; speedup vs baseline: 1.3725x; 1.3725x over previous
//
#include <hip/hip_runtime.h>
#include <hip/hip_bf16.h>
#include <cstdint>

#define NB    8
#define NPTS  4096
#define NL    8              // candidate lists per row (4 strips x 2 col-halves)
#define NPH2  32             // phases per block (2048 cols / 64)
#define SLOTS 9              // defer-buffer slots/thread (vote per 4 cols, thr 5: max cnt 8)
#define SCST  65             // score-tile row stride: bank=(r+c)%32, 2-way free on scan reads

typedef __attribute__((ext_vector_type(8))) short bf16x8;
typedef __attribute__((ext_vector_type(4))) float f32x4;

// insert r,m into sorted-descending top-N (D[0]=worst). Caller checks r < D[0].
template <int N>
__device__ __forceinline__ void insertN(float (&D)[N], int (&M)[N], float r, int m) {
  bool c[N];
#pragma unroll
  for (int i = 0; i < N; ++i) c[i] = (D[i] > r);
#pragma unroll
  for (int i = 0; i < N; ++i) {
    bool  cn = (i < N - 1) ? c[i + 1] : false;
    float dn = (i < N - 1) ? D[i + 1] : 0.f;
    int   mn = (i < N - 1) ? M[i + 1] : 0;
    D[i] = cn ? dn : (c[i] ? r : D[i]);
    M[i] = cn ? mn : (c[i] ? m : M[i]);
  }
}

// same, packed-u32 keys (unsigned compare), no index array
template <int N>
__device__ __forceinline__ void insertU(unsigned (&D)[N], unsigned u) {
  bool c[N];
#pragma unroll
  for (int i = 0; i < N; ++i) c[i] = (D[i] > u);
#pragma unroll
  for (int i = 0; i < N; ++i) {
    bool     cn = (i < N - 1) ? c[i + 1] : false;
    unsigned dn = (i < N - 1) ? D[i + 1] : 0u;
    D[i] = cn ? dn : (c[i] ? u : D[i]);
  }
}

// monotone float->uint map (ascending u <=> ascending f)
__device__ __forceinline__ unsigned f2mono(float f) {
  unsigned b = __float_as_uint(f);
  return b ^ (((int)b < 0) ? 0xFFFFFFFFu : 0x80000000u);
}

// ---------------------------------------------------------------------------
// A: x [B,C,N] -> XT fp32 [B,N,64], XH/XL bf16 split [B,N,64], sq[b,n]
// ---------------------------------------------------------------------------
__global__ __launch_bounds__(256) void k_prep(const float* __restrict__ x,
                                              float* __restrict__ xt,
                                              __hip_bfloat16* __restrict__ xh,
                                              __hip_bfloat16* __restrict__ xl,
                                              float* __restrict__ sq) {
  __shared__ float tile[64][65];
  const int b  = blockIdx.y;
  const int n0 = blockIdx.x * 64;
  const int t  = threadIdx.x;
#pragma unroll
  for (int i = 0; i < 16; ++i) {
    int lin = i * 256 + t;
    int c = lin >> 6, j = lin & 63;
    tile[j][c] = x[(size_t)b * 64 * NPTS + (size_t)c * NPTS + n0 + j];
  }
  __syncthreads();
#pragma unroll
  for (int i = 0; i < 16; ++i) {
    int lin = i * 256 + t;
    int j = lin >> 6, c = lin & 63;
    float v = tile[j][c];
    size_t o = ((size_t)b * NPTS + n0 + j) * 64 + c;
    xt[o] = v;
    __hip_bfloat16 h = __float2bfloat16(v);
    xh[o] = h;
    xl[o] = __float2bfloat16(v - __bfloat162float(h));
  }
  if (t < 64) {
    float s = 0.f;
#pragma unroll
    for (int c = 0; c < 64; ++c) { float v = tile[t][c]; s = fmaf(v, v, s); }
    sq[b * NPTS + t + n0] = s;
  }
}

// ---------------------------------------------------------------------------
// B: register-pipelined MFMA Gram + fused approx top-16 per (row, strip).
// Block: 64 rows x 2048 cols (col-half), 256 thr / 4 waves. 32 phases x 64
// cols. Window between barriers: [write sc(p)] || [loads+MFMA(p+1)] |barrier|
// [scan(p)] -> global-load latency and MFMA chain overlap scan + barrier.
// Output: packed u32 (mono-key top-20 bits | col idx 12 bits) x16 per list.
// ---------------------------------------------------------------------------
__global__ __launch_bounds__(256, 4) void k_gram(const __hip_bfloat16* __restrict__ xh,
                                                 const __hip_bfloat16* __restrict__ xl,
                                                 const float* __restrict__ sq,
                                                 unsigned* __restrict__ part) {
  __shared__ float sc[64 * SCST];                 // 16.6 KB
  __shared__ float bufr[256 * SLOTS];             // 9.2 KB
  __shared__ unsigned short bufm[256 * SLOTS];    // 4.6 KB

  const int tid  = threadIdx.x;
  const int w    = tid >> 6;                      // wave 0..3 = row-tile = scan strip
  const int lane = tid & 63;
  const int quad = lane >> 4, l15 = lane & 15;
  const int rb   = blockIdx.x;                    // 0..63 row-block
  const int ch   = blockIdx.y;                    // 0..1 col-half
  const int b    = blockIdx.z;                    // 0..7
  const size_t xbase = (size_t)b * NPTS * 64;
  const int c0   = ch * 2048;

  // persistent A fragments: rows rb*64 + w*16 + l15, A[m=lane&15][k=quad*8+j]
  const __hip_bfloat16* ah = xh + xbase + (size_t)(rb * 64 + w * 16 + l15) * 64 + quad * 8;
  const __hip_bfloat16* al = xl + xbase + (size_t)(rb * 64 + w * 16 + l15) * 64 + quad * 8;
  const bf16x8 a_h0 = *(const bf16x8*)(ah);
  const bf16x8 a_h1 = *(const bf16x8*)(ah + 32);
  const bf16x8 a_l0 = *(const bf16x8*)(al);
  const bf16x8 a_l1 = *(const bf16x8*)(al + 32);

  const int r     = lane;                         // scan row
  const int nself = rb * 64 + r;                  // self col (within batch)
  float D[16]; int M[16];
#pragma unroll
  for (int i = 0; i < 16; ++i) { D[i] = 1e30f; M[i] = 0; }
  int cnt = 0;

  auto phase = [&](int p, f32x4 (&out)[4]) {
    const int m0 = c0 + p * 64;
#pragma unroll
    for (int ct = 0; ct < 4; ++ct) {
      const int col = m0 + ct * 16 + l15;
      const __hip_bfloat16* bh = xh + xbase + (size_t)col * 64 + quad * 8;
      const __hip_bfloat16* bl = xl + xbase + (size_t)col * 64 + quad * 8;
      bf16x8 bh0 = *(const bf16x8*)(bh);
      bf16x8 bh1 = *(const bf16x8*)(bh + 32);
      bf16x8 bl0 = *(const bf16x8*)(bl);
      bf16x8 bl1 = *(const bf16x8*)(bl + 32);
      float sv = sq[b * NPTS + col];
      f32x4 acc = { -0.5f * sv, -0.5f * sv, -0.5f * sv, -0.5f * sv };
      acc = __builtin_amdgcn_mfma_f32_16x16x32_bf16(a_h0, bh0, acc, 0, 0, 0);
      acc = __builtin_amdgcn_mfma_f32_16x16x32_bf16(a_h1, bh1, acc, 0, 0, 0);
      acc = __builtin_amdgcn_mfma_f32_16x16x32_bf16(a_h0, bl0, acc, 0, 0, 0);
      acc = __builtin_amdgcn_mfma_f32_16x16x32_bf16(a_h1, bl1, acc, 0, 0, 0);
      acc = __builtin_amdgcn_mfma_f32_16x16x32_bf16(a_l0, bh0, acc, 0, 0, 0);
      acc = __builtin_amdgcn_mfma_f32_16x16x32_bf16(a_l1, bh1, acc, 0, 0, 0);
      out[ct] = acc;
    }
  };

  auto flush = [&]() {
#pragma unroll 1
    for (int i = 0; i < SLOTS; ++i) {
      if (__ballot(i < cnt) == 0ull) break;
      if (i < cnt) {
        float rr = bufr[tid * SLOTS + i];
        int   mm = bufm[tid * SLOTS + i];
        if (rr < D[0]) insertN<16>(D, M, rr, mm);
      }
    }
    cnt = 0;
  };

  f32x4 cur[4], nxt[4];
  phase(0, cur);

#pragma unroll 2
  for (int p = 0; p < NPH2; ++p) {
    __syncthreads();                              // sc free (prev scan done)
    {
      const int rbase = w * 16 + quad * 4;
#pragma unroll
      for (int ct = 0; ct < 4; ++ct)
#pragma unroll
        for (int i = 0; i < 4; ++i)
          sc[(rbase + i) * SCST + ct * 16 + l15] = -2.f * cur[ct][i];
    }
    if (p + 1 < NPH2) phase(p + 1, nxt);          // overlaps barrier + scan
    __syncthreads();                              // sc visible
    const float* srow = sc + r * SCST + w * 16;
    const int    mb   = c0 + p * 64 + w * 16;
#pragma unroll
    for (int g = 0; g < 4; ++g) {
#pragma unroll
      for (int j = 0; j < 4; ++j) {
        float s    = srow[g * 4 + j];
        int   mcol = mb + g * 4 + j;
        bool pass = (s < D[0]) & (mcol != nself);
        if (pass) {
          bufr[tid * SLOTS + cnt] = s;
          bufm[tid * SLOTS + cnt] = (unsigned short)mcol;
          cnt++;
        }
      }
      if (__any(cnt >= 5)) flush();
    }
#pragma unroll
    for (int ct = 0; ct < 4; ++ct) cur[ct] = nxt[ct];
  }
  flush();

  const size_t base = ((size_t)(b * NPTS + nself) * NL + (ch * 4 + w)) * 16;
#pragma unroll
  for (int i = 0; i < 16; ++i)
    part[base + i] = (f2mono(D[i]) & 0xFFFFF000u) | (unsigned)M[i];
}

// ---------------------------------------------------------------------------
// C: merge 8 packed lists -> approx top-20 candidate indices per row
// ---------------------------------------------------------------------------
__global__ __launch_bounds__(256) void k_merge(const unsigned* __restrict__ part,
                                               int* __restrict__ cand) {
  const int row = blockIdx.x * 256 + threadIdx.x;   // 0..32767
  unsigned D[20];
#pragma unroll
  for (int i = 0; i < 20; ++i) D[i] = 0xFFFFFFFFu;
  const uint4* pr = (const uint4*)(part + (size_t)row * (NL * 16));
#pragma unroll 1
  for (int i = 0; i < NL * 4; ++i) {
    uint4 v = pr[i];
    if (v.x < D[0]) insertU<20>(D, v.x);
    if (v.y < D[0]) insertU<20>(D, v.y);
    if (v.z < D[0]) insertU<20>(D, v.z);
    if (v.w < D[0]) insertU<20>(D, v.w);
  }
#pragma unroll
  for (int i = 0; i < 20; ++i) cand[(size_t)row * 20 + i] = (int)(D[i] & 0xFFFu);
}

// ---------------------------------------------------------------------------
// D: exact fp32 rerank of 20 candidates -> final 16 knn indices (order-free:
// downstream is max-pool). Wave per row; lane = channel; shfl-butterfly dot.
// ---------------------------------------------------------------------------
__global__ __launch_bounds__(256) void k_rerank(const float* __restrict__ xt,
                                                const float* __restrict__ sq,
                                                const int* __restrict__ cand,
                                                int* __restrict__ knn) {
  const int w    = threadIdx.x >> 6;
  const int lane = threadIdx.x & 63;
  const int row  = blockIdx.x * 4 + w;          // 0..32767
  const int b    = row >> 12;
  const float* xb = xt + (size_t)b * NPTS * 64;
  const float cen = xt[(size_t)row * 64 + lane];
  const int mc = cand[(size_t)row * 20 + (lane < 20 ? lane : 0)];
  float rall[20]; int mall[20];
#pragma unroll
  for (int c = 0; c < 20; ++c) {
    int m = __shfl(mc, c);
    float v = cen * xb[(size_t)m * 64 + lane];
#pragma unroll
    for (int off = 32; off; off >>= 1) v += __shfl_xor(v, off);
    rall[c] = sq[b * NPTS + m] - 2.f * v;   // exact fp32 rank key
    mall[c] = m;
  }
  if (lane < 20) {
    float my = rall[lane]; int mym = mall[lane];
    int rk = 0;
#pragma unroll
    for (int j = 0; j < 20; ++j)
      rk += (rall[j] < my) || ((rall[j] == my) && (mall[j] < mym));
    if (rk < 16) knn[(size_t)row * 16 + rk] = mall[lane];
  }
}

// ---------------------------------------------------------------------------
// E: P[n][o] = W1[o]·xt[n] ;  Q[n][o] = (W2-W1)[o]·xt[n] + b1[o] + b2[o]
// ---------------------------------------------------------------------------
__global__ __launch_bounds__(256, 4) void k_pq(const float* __restrict__ xt,
                                               const float* __restrict__ W1,
                                               const float* __restrict__ b1,
                                               const float* __restrict__ W2,
                                               const float* __restrict__ b2,
                                               float* __restrict__ P,
                                               float* __restrict__ Q) {
  const int gn = blockIdx.x * 256 + threadIdx.x;
  const int o0 = blockIdx.y * 16;
  float cen[64];
  {
    const float4* s4 = (const float4*)(xt + (size_t)gn * 64);
    float4* c4 = (float4*)cen;
#pragma unroll
    for (int i = 0; i < 16; ++i) c4[i] = s4[i];
  }
#pragma unroll 1
  for (int oi = 0; oi < 16; ++oi) {
    const int o = o0 + oi;
    float p = 0.f, q2 = 0.f;
#pragma unroll
    for (int c = 0; c < 64; ++c) {
      p  = fmaf(W1[o * 64 + c], cen[c], p);
      q2 = fmaf(W2[o * 64 + c], cen[c], q2);
    }
    P[(size_t)gn * 64 + o] = p;
    Q[(size_t)gn * 64 + o] = q2 - p + b1[o] + b2[o];
  }
}

// ---------------------------------------------------------------------------
// F: y[n][o] = relu(max_k (Q[n][o] + P[knn[n][k]][o]))
// ---------------------------------------------------------------------------
__global__ __launch_bounds__(256) void k_out(const float* __restrict__ P,
                                             const float* __restrict__ Q,
                                             const int* __restrict__ knn,
                                             float* __restrict__ out) {
  __shared__ float tile[64][65];
  const int b    = blockIdx.y;
  const int n0   = blockIdx.x * 64;
  const int wave = threadIdx.x >> 6;
  const int lane = threadIdx.x & 63;
  for (int i = 0; i < 16; ++i) {
    const int nl = wave * 16 + i;
    const int gn = b * NPTS + n0 + nl;
    float acc = -1e30f;
    const float qv = Q[(size_t)gn * 64 + lane];
    const int* id = knn + (size_t)gn * 16;
#pragma unroll
    for (int k = 0; k < 16; ++k) {
      int m = id[k];
      float p = P[((size_t)b * NPTS + m) * 64 + lane];
      acc = fmaxf(acc, qv + p);
    }
    tile[nl][lane] = fmaxf(acc, 0.f);
  }
  __syncthreads();
#pragma unroll
  for (int i = 0; i < 16; ++i) {
    const int o = i * 4 + wave;
    out[((size_t)b * 64 + o) * NPTS + n0 + lane] = tile[lane][o];
  }
}

// ---------------------------------------------------------------------------
extern "C" void kernel_launch(void* const* d_in, const int* in_sizes, int n_in,
                              void* d_out, int out_size, void* d_ws, size_t ws_size,
                              hipStream_t stream) {
  const float* x  = (const float*)d_in[0];
  const float* W1 = (const float*)d_in[1];
  const float* b1 = (const float*)d_in[2];
  const float* W2 = (const float*)d_in[3];
  const float* b2 = (const float*)d_in[4];
  float* out = (float*)d_out;

  // workspace carve-up, ~38.4 MB (R1 proved >=44.4 MB usable)
  float* ws = (float*)d_ws;
  const size_t NPT_ALL = (size_t)NB * NPTS;                // 32768
  float*          XT   = ws;                               // 2,097,152 f
  float*          SQ   = XT + NPT_ALL * 64;                //    32,768 f
  __hip_bfloat16* XH   = (__hip_bfloat16*)(SQ + NPT_ALL);  // 2,097,152 bf16
  __hip_bfloat16* XL   = XH + NPT_ALL * 64;                // 2,097,152 bf16
  unsigned*       PART = (unsigned*)(XL + NPT_ALL * 64);   // 4,194,304 u32
  int*            CAND = (int*)(PART + NPT_ALL * NL * 16); //   655,360 i
  int*            KNN  = CAND + NPT_ALL * 20;              //   524,288 i
  float*          Pm   = (float*)PART;   // overlay: PART dead after merge
  float*          Qm   = (float*)XH;     // overlay: XH/XL dead after gram

  k_prep  <<<dim3(NPTS / 64, NB), 256, 0, stream>>>(x, XT, XH, XL, SQ);
  k_gram  <<<dim3(64, 2, NB), 256, 0, stream>>>(XH, XL, SQ, PART);
  k_merge <<<dim3(NPT_ALL / 256), 256, 0, stream>>>(PART, CAND);
  k_rerank<<<dim3(NPT_ALL / 4), 256, 0, stream>>>(XT, SQ, CAND, KNN);
  k_pq    <<<dim3(NPT_ALL / 256, 4), 256, 0, stream>>>(XT, W1, b1, W2, b2, Pm, Qm);
  k_out   <<<dim3(NPTS / 64, NB), 256, 0, stream>>>(Pm, Qm, KNN, out);
}

// Round 6
// 518.027 us; speedup vs baseline: 1.3861x; 1.0099x over previous
//
#include <hip/hip_runtime.h>
#include <hip/hip_bf16.h>
#include <cstdint>

#define NB    8
#define NPTS  4096
#define NL    8              // candidate lists per row (4 strips x 2 col-halves)
#define NPH2  32             // phases per block (2048 cols / 64)
#define SLOTS 8              // defer-buffer slots/thread (vote>=5 per 4 cols -> max 8)
#define SCST  65             // score-tile row stride: 2-way banks on scan reads (free)
#define SENTKEY 0xFF61B000u  // packed mono key of ~3e38 (finite after mono2f)

typedef __attribute__((ext_vector_type(8))) short bf16x8;
typedef __attribute__((ext_vector_type(4))) float f32x4;

// insert u into sorted-descending top-N of packed u32 keys (D[0]=worst).
template <int N>
__device__ __forceinline__ void insertU(unsigned (&D)[N], unsigned u) {
  bool c[N];
#pragma unroll
  for (int i = 0; i < N; ++i) c[i] = (D[i] > u);
#pragma unroll
  for (int i = 0; i < N; ++i) {
    bool     cn = (i < N - 1) ? c[i + 1] : false;
    unsigned dn = (i < N - 1) ? D[i + 1] : 0u;
    D[i] = cn ? dn : (c[i] ? u : D[i]);
  }
}

// monotone float<->uint maps (ascending u <=> ascending f)
__device__ __forceinline__ unsigned f2mono(float f) {
  unsigned b = __float_as_uint(f);
  return b ^ (((int)b < 0) ? 0xFFFFFFFFu : 0x80000000u);
}
__device__ __forceinline__ float mono2f(unsigned u) {
  return __uint_as_float(u ^ (((int)u < 0) ? 0x80000000u : 0xFFFFFFFFu));
}

// ---------------------------------------------------------------------------
// A: x [B,C,N] -> XT fp32 [B,N,64], XH/XL bf16 split [B,N,64], sq[b,n]
// ---------------------------------------------------------------------------
__global__ __launch_bounds__(256) void k_prep(const float* __restrict__ x,
                                              float* __restrict__ xt,
                                              __hip_bfloat16* __restrict__ xh,
                                              __hip_bfloat16* __restrict__ xl,
                                              float* __restrict__ sq) {
  __shared__ float tile[64][65];
  const int b  = blockIdx.y;
  const int n0 = blockIdx.x * 64;
  const int t  = threadIdx.x;
#pragma unroll
  for (int i = 0; i < 16; ++i) {
    int lin = i * 256 + t;
    int c = lin >> 6, j = lin & 63;
    tile[j][c] = x[(size_t)b * 64 * NPTS + (size_t)c * NPTS + n0 + j];
  }
  __syncthreads();
#pragma unroll
  for (int i = 0; i < 16; ++i) {
    int lin = i * 256 + t;
    int j = lin >> 6, c = lin & 63;
    float v = tile[j][c];
    size_t o = ((size_t)b * NPTS + n0 + j) * 64 + c;
    xt[o] = v;
    __hip_bfloat16 h = __float2bfloat16(v);
    xh[o] = h;
    xl[o] = __float2bfloat16(v - __bfloat162float(h));
  }
  if (t < 64) {
    float s = 0.f;
#pragma unroll
    for (int c = 0; c < 64; ++c) { float v = tile[t][c]; s = fmaf(v, v, s); }
    sq[b * NPTS + t + n0] = s;
  }
}

// ---------------------------------------------------------------------------
// B: register-pipelined MFMA Gram + fused approx top-16 per (row, strip).
// Selection on packed u32 keys (mono-score hi-20 | col 12). Defer buffer is
// one u32/entry; flush reads all 8 slots via 2x ds_read_b128 (one wait).
// ---------------------------------------------------------------------------
__global__ __launch_bounds__(256, 5) void k_gram(const __hip_bfloat16* __restrict__ xh,
                                                 const __hip_bfloat16* __restrict__ xl,
                                                 const float* __restrict__ sq,
                                                 unsigned* __restrict__ part) {
  __shared__ float sc[64 * SCST];                 // 16640 B
  __shared__ unsigned bufu[256 * SLOTS];          //  8192 B

  const int tid  = threadIdx.x;
  const int w    = tid >> 6;                      // wave = row-tile = scan strip
  const int lane = tid & 63;
  const int quad = lane >> 4, l15 = lane & 15;
  const int rb   = blockIdx.x;                    // 0..63 row-block
  const int ch   = blockIdx.y;                    // 0..1 col-half
  const int b    = blockIdx.z;                    // 0..7
  const size_t xbase = (size_t)b * NPTS * 64;
  const int c0   = ch * 2048;

  // persistent A fragments: rows rb*64 + w*16 + l15, A[m=lane&15][k=quad*8+j]
  const __hip_bfloat16* ah = xh + xbase + (size_t)(rb * 64 + w * 16 + l15) * 64 + quad * 8;
  const __hip_bfloat16* al = xl + xbase + (size_t)(rb * 64 + w * 16 + l15) * 64 + quad * 8;
  const bf16x8 a_h0 = *(const bf16x8*)(ah);
  const bf16x8 a_h1 = *(const bf16x8*)(ah + 32);
  const bf16x8 a_l0 = *(const bf16x8*)(al);
  const bf16x8 a_l1 = *(const bf16x8*)(al + 32);

  const int r     = lane;                         // scan row
  const int nself = rb * 64 + r;                  // self col (within batch)
  unsigned D[16];
#pragma unroll
  for (int i = 0; i < 16; ++i) D[i] = SENTKEY;
  float thrf = 1e30f;
  int cnt = 0;

  auto phase = [&](int p, f32x4 (&out)[4]) {
    const int m0 = c0 + p * 64;
#pragma unroll
    for (int ct = 0; ct < 4; ++ct) {
      const int col = m0 + ct * 16 + l15;
      const __hip_bfloat16* bh = xh + xbase + (size_t)col * 64 + quad * 8;
      const __hip_bfloat16* bl = xl + xbase + (size_t)col * 64 + quad * 8;
      bf16x8 bh0 = *(const bf16x8*)(bh);
      bf16x8 bh1 = *(const bf16x8*)(bh + 32);
      bf16x8 bl0 = *(const bf16x8*)(bl);
      bf16x8 bl1 = *(const bf16x8*)(bl + 32);
      float sv = sq[b * NPTS + col];
      f32x4 acc = { -0.5f * sv, -0.5f * sv, -0.5f * sv, -0.5f * sv };
      acc = __builtin_amdgcn_mfma_f32_16x16x32_bf16(a_h0, bh0, acc, 0, 0, 0);
      acc = __builtin_amdgcn_mfma_f32_16x16x32_bf16(a_h1, bh1, acc, 0, 0, 0);
      acc = __builtin_amdgcn_mfma_f32_16x16x32_bf16(a_h0, bl0, acc, 0, 0, 0);
      acc = __builtin_amdgcn_mfma_f32_16x16x32_bf16(a_h1, bl1, acc, 0, 0, 0);
      acc = __builtin_amdgcn_mfma_f32_16x16x32_bf16(a_l0, bh0, acc, 0, 0, 0);
      acc = __builtin_amdgcn_mfma_f32_16x16x32_bf16(a_l1, bh1, acc, 0, 0, 0);
      out[ct] = acc;
    }
  };

  auto flush = [&]() {
    const uint4* bp = (const uint4*)(bufu + tid * SLOTS);
    uint4 v0 = bp[0], v1 = bp[1];                 // one lgkm wait, batched
    unsigned ee[8] = { v0.x, v0.y, v0.z, v0.w, v1.x, v1.y, v1.z, v1.w };
#pragma unroll
    for (int i = 0; i < 8; ++i) {
      if (__ballot(i < cnt) == 0ull) break;
      if (i < cnt) { unsigned u = ee[i]; if (u < D[0]) insertU<16>(D, u); }
    }
    cnt = 0;
    thrf = mono2f(D[0] | 0xFFFu);                 // conservative float mirror
  };

  f32x4 cur[4], nxt[4];
  phase(0, cur);

#pragma unroll 1
  for (int p = 0; p < NPH2; ++p) {
    __syncthreads();                              // sc free (prev scan done)
    {
      const int rbase = w * 16 + quad * 4;
#pragma unroll
      for (int ct = 0; ct < 4; ++ct)
#pragma unroll
        for (int i = 0; i < 4; ++i)
          sc[(rbase + i) * SCST + ct * 16 + l15] = -2.f * cur[ct][i];
    }
    if (p + 1 < NPH2) phase(p + 1, nxt);          // overlaps barrier + scan
    __syncthreads();                              // sc visible
    const float* srow = sc + r * SCST + w * 16;
    const int    mb   = c0 + p * 64 + w * 16;
#pragma unroll 1
    for (int g = 0; g < 4; ++g) {
#pragma unroll
      for (int j = 0; j < 4; ++j) {
        float s    = srow[g * 4 + j];
        int   mcol = mb + g * 4 + j;
        bool pass = (s <= thrf) & (mcol != nself);
        if (pass) {
          bufu[tid * SLOTS + cnt] = (f2mono(s) & 0xFFFFF000u) | (unsigned)mcol;
          cnt++;
        }
      }
      if (__any(cnt >= 5)) flush();
    }
#pragma unroll
    for (int ct = 0; ct < 4; ++ct) cur[ct] = nxt[ct];
  }
  flush();

  const size_t base = ((size_t)(b * NPTS + nself) * NL + (ch * 4 + w)) * 16;
#pragma unroll
  for (int i = 0; i < 16; ++i) part[base + i] = D[i];
}

// ---------------------------------------------------------------------------
// C: fused merge (8 lists -> approx top-20) + exact fp32 rerank -> knn[16].
// Block = 64 rows: phase1 threads 0..63 merge one row each (packed keys);
// phase2 wave-per-row (16 rows/wave), shfl-butterfly exact distances.
// ---------------------------------------------------------------------------
__global__ __launch_bounds__(256) void k_msel(const unsigned* __restrict__ part,
                                              const float* __restrict__ xt,
                                              const float* __restrict__ sq,
                                              int* __restrict__ knn) {
  __shared__ unsigned short cidx[64][20];
  const int t    = threadIdx.x;
  const int row0 = blockIdx.x * 64;
  if (t < 64) {
    unsigned D[20];
#pragma unroll
    for (int i = 0; i < 20; ++i) D[i] = 0xFFFFFFFFu;
    const uint4* pr = (const uint4*)(part + (size_t)(row0 + t) * (NL * 16));
#pragma unroll 1
    for (int i = 0; i < NL * 4; ++i) {
      uint4 v = pr[i];
      if (v.x < D[0]) insertU<20>(D, v.x);
      if (v.y < D[0]) insertU<20>(D, v.y);
      if (v.z < D[0]) insertU<20>(D, v.z);
      if (v.w < D[0]) insertU<20>(D, v.w);
    }
#pragma unroll
    for (int i = 0; i < 20; ++i) cidx[t][i] = (unsigned short)(D[i] & 0xFFFu);
  }
  __syncthreads();
  const int w = t >> 6, lane = t & 63;
#pragma unroll 1
  for (int rr = w * 16; rr < w * 16 + 16; ++rr) {
    const int row = row0 + rr;
    const int b   = row >> 12;
    const float* xb = xt + (size_t)b * NPTS * 64;
    const float cen = xt[(size_t)row * 64 + lane];
    float rall[20]; int mall[20];
#pragma unroll
    for (int c = 0; c < 20; ++c) {
      int m = cidx[rr][c];                        // within-batch col (broadcast)
      float v = cen * xb[(size_t)m * 64 + lane];
#pragma unroll
      for (int off = 32; off; off >>= 1) v += __shfl_xor(v, off);
      rall[c] = sq[b * NPTS + m] - 2.f * v;       // exact fp32 rank key
      mall[c] = m;
    }
    if (lane < 20) {
      float my = rall[lane]; int mym = mall[lane];
      int rk = 0;
#pragma unroll
      for (int j = 0; j < 20; ++j)
        rk += (rall[j] < my) || ((rall[j] == my) && (mall[j] < mym));
      if (rk < 16) knn[(size_t)row * 16 + rk] = mall[lane];
    }
  }
}

// ---------------------------------------------------------------------------
// D: P[n][o] = W1[o]·xt[n] ;  Q[n][o] = (W2-W1)[o]·xt[n] + b1[o] + b2[o]
// ---------------------------------------------------------------------------
__global__ __launch_bounds__(256, 4) void k_pq(const float* __restrict__ xt,
                                               const float* __restrict__ W1,
                                               const float* __restrict__ b1,
                                               const float* __restrict__ W2,
                                               const float* __restrict__ b2,
                                               float* __restrict__ P,
                                               float* __restrict__ Q) {
  const int gn = blockIdx.x * 256 + threadIdx.x;
  const int o0 = blockIdx.y * 16;
  float cen[64];
  {
    const float4* s4 = (const float4*)(xt + (size_t)gn * 64);
    float4* c4 = (float4*)cen;
#pragma unroll
    for (int i = 0; i < 16; ++i) c4[i] = s4[i];
  }
#pragma unroll 1
  for (int oi = 0; oi < 16; ++oi) {
    const int o = o0 + oi;
    float p = 0.f, q2 = 0.f;
#pragma unroll
    for (int c = 0; c < 64; ++c) {
      p  = fmaf(W1[o * 64 + c], cen[c], p);
      q2 = fmaf(W2[o * 64 + c], cen[c], q2);
    }
    P[(size_t)gn * 64 + o] = p;
    Q[(size_t)gn * 64 + o] = q2 - p + b1[o] + b2[o];
  }
}

// ---------------------------------------------------------------------------
// E: y[n][o] = relu(max_k (Q[n][o] + P[knn[n][k]][o]))
// ---------------------------------------------------------------------------
__global__ __launch_bounds__(256) void k_out(const float* __restrict__ P,
                                             const float* __restrict__ Q,
                                             const int* __restrict__ knn,
                                             float* __restrict__ out) {
  __shared__ float tile[64][65];
  const int b    = blockIdx.y;
  const int n0   = blockIdx.x * 64;
  const int wave = threadIdx.x >> 6;
  const int lane = threadIdx.x & 63;
  for (int i = 0; i < 16; ++i) {
    const int nl = wave * 16 + i;
    const int gn = b * NPTS + n0 + nl;
    float acc = -1e30f;
    const float qv = Q[(size_t)gn * 64 + lane];
    const int* id = knn + (size_t)gn * 16;
#pragma unroll
    for (int k = 0; k < 16; ++k) {
      int m = id[k];
      float p = P[((size_t)b * NPTS + m) * 64 + lane];
      acc = fmaxf(acc, qv + p);
    }
    tile[nl][lane] = fmaxf(acc, 0.f);
  }
  __syncthreads();
#pragma unroll
  for (int i = 0; i < 16; ++i) {
    const int o = i * 4 + wave;
    out[((size_t)b * 64 + o) * NPTS + n0 + lane] = tile[lane][o];
  }
}

// ---------------------------------------------------------------------------
extern "C" void kernel_launch(void* const* d_in, const int* in_sizes, int n_in,
                              void* d_out, int out_size, void* d_ws, size_t ws_size,
                              hipStream_t stream) {
  const float* x  = (const float*)d_in[0];
  const float* W1 = (const float*)d_in[1];
  const float* b1 = (const float*)d_in[2];
  const float* W2 = (const float*)d_in[3];
  const float* b2 = (const float*)d_in[4];
  float* out = (float*)d_out;

  // workspace ~35 MB (<= proven 43.7 MB)
  float* ws = (float*)d_ws;
  const size_t NPT_ALL = (size_t)NB * NPTS;                // 32768
  float*          XT   = ws;                               // 8 MB
  float*          SQ   = XT + NPT_ALL * 64;                // 0.13 MB
  __hip_bfloat16* XH   = (__hip_bfloat16*)(SQ + NPT_ALL);  // 4 MB
  __hip_bfloat16* XL   = XH + NPT_ALL * 64;                // 4 MB
  unsigned*       PART = (unsigned*)(XL + NPT_ALL * 64);   // 16.8 MB
  int*            KNN  = (int*)(PART + NPT_ALL * NL * 16); // 2 MB
  float*          Pm   = (float*)PART;   // overlay: PART dead after msel
  float*          Qm   = (float*)XH;     // overlay: XH/XL dead after gram

  k_prep <<<dim3(NPTS / 64, NB), 256, 0, stream>>>(x, XT, XH, XL, SQ);
  k_gram <<<dim3(64, 2, NB), 256, 0, stream>>>(XH, XL, SQ, PART);
  k_msel <<<dim3(NPT_ALL / 64), 256, 0, stream>>>(PART, XT, SQ, KNN);
  k_pq   <<<dim3(NPT_ALL / 256, 4), 256, 0, stream>>>(XT, W1, b1, W2, b2, Pm, Qm);
  k_out  <<<dim3(NPTS / 64, NB), 256, 0, stream>>>(Pm, Qm, KNN, out);
}

// Round 7
// 513.296 us; speedup vs baseline: 1.3989x; 1.0092x over previous
//
#include <hip/hip_runtime.h>
#include <hip/hip_bf16.h>
#include <cstdint>

#define NB    8
#define NPTS  4096
#define NQ    4              // col-quarters (blockIdx.y)
#define NPH   16             // phases per block (1024 cols / 64)
#define SLOTS 12             // defer slots/thread (vote per 8 cols, thr 4: max 3+8=11)
#define SCST  65             // score-tile row stride (2-way banks = free)
#define PROW  72             // part row stride in u32 (4 quarters x 18)
#define SENTKEY 0xFF61B000u  // packed mono key of ~3e38

typedef __attribute__((ext_vector_type(8))) short bf16x8;
typedef __attribute__((ext_vector_type(4))) float f32x4;

// insert u into sorted-descending top-N of packed u32 keys (D[0]=worst).
template <int N>
__device__ __forceinline__ void insertU(unsigned (&D)[N], unsigned u) {
  bool c[N];
#pragma unroll
  for (int i = 0; i < N; ++i) c[i] = (D[i] > u);
#pragma unroll
  for (int i = 0; i < N; ++i) {
    bool     cn = (i < N - 1) ? c[i + 1] : false;
    unsigned dn = (i < N - 1) ? D[i + 1] : 0u;
    D[i] = cn ? dn : (c[i] ? u : D[i]);
  }
}

// monotone float<->uint maps (ascending u <=> ascending f)
__device__ __forceinline__ unsigned f2mono(float f) {
  unsigned b = __float_as_uint(f);
  return b ^ (((int)b < 0) ? 0xFFFFFFFFu : 0x80000000u);
}
__device__ __forceinline__ float mono2f(unsigned u) {
  return __uint_as_float(u ^ (((int)u < 0) ? 0x80000000u : 0xFFFFFFFFu));
}

// ---------------------------------------------------------------------------
// A: x [B,C,N] -> XT fp32 [B,N,64], XH/XL bf16 split [B,N,64], sq[b,n]
// ---------------------------------------------------------------------------
__global__ __launch_bounds__(256) void k_prep(const float* __restrict__ x,
                                              float* __restrict__ xt,
                                              __hip_bfloat16* __restrict__ xh,
                                              __hip_bfloat16* __restrict__ xl,
                                              float* __restrict__ sq) {
  __shared__ float tile[64][65];
  const int b  = blockIdx.y;
  const int n0 = blockIdx.x * 64;
  const int t  = threadIdx.x;
#pragma unroll
  for (int i = 0; i < 16; ++i) {
    int lin = i * 256 + t;
    int c = lin >> 6, j = lin & 63;
    tile[j][c] = x[(size_t)b * 64 * NPTS + (size_t)c * NPTS + n0 + j];
  }
  __syncthreads();
#pragma unroll
  for (int i = 0; i < 16; ++i) {
    int lin = i * 256 + t;
    int j = lin >> 6, c = lin & 63;
    float v = tile[j][c];
    size_t o = ((size_t)b * NPTS + n0 + j) * 64 + c;
    xt[o] = v;
    __hip_bfloat16 h = __float2bfloat16(v);
    xh[o] = h;
    xl[o] = __float2bfloat16(v - __bfloat162float(h));
  }
  if (t < 64) {
    float s = 0.f;
#pragma unroll
    for (int c = 0; c < 64; ++c) { float v = tile[t][c]; s = fmaf(v, v, s); }
    sq[b * NPTS + t + n0] = s;
  }
}

// ---------------------------------------------------------------------------
// B: register-pipelined MFMA Gram + fused approx top-16 per (row, strip).
// Block: 64 rows x 1024 cols (quarter), 256 thr. Slot-major defer buffer
// (conflict-free). Epilogue merges the 4 wave-lists -> top-18 per quarter.
// ---------------------------------------------------------------------------
__global__ __launch_bounds__(256, 5) void k_gram(const __hip_bfloat16* __restrict__ xh,
                                                 const __hip_bfloat16* __restrict__ xl,
                                                 const float* __restrict__ sq,
                                                 unsigned* __restrict__ part) {
  __shared__ float sc[64 * SCST];                 // 16640 B (reused by epilogue)
  __shared__ unsigned bufu[SLOTS * 256];          // 12288 B, slot-major

  const int tid  = threadIdx.x;
  const int w    = tid >> 6;                      // wave = row-tile = scan strip
  const int lane = tid & 63;
  const int quad = lane >> 4, l15 = lane & 15;
  const int rb   = blockIdx.x;                    // 0..63 row-block
  const int q    = blockIdx.y;                    // 0..3 col-quarter
  const int b    = blockIdx.z;                    // 0..7
  const size_t xbase = (size_t)b * NPTS * 64;
  const int c0   = q * 1024;

  // persistent A fragments: rows rb*64 + w*16 + l15, A[m=lane&15][k=quad*8+j]
  const __hip_bfloat16* ah = xh + xbase + (size_t)(rb * 64 + w * 16 + l15) * 64 + quad * 8;
  const __hip_bfloat16* al = xl + xbase + (size_t)(rb * 64 + w * 16 + l15) * 64 + quad * 8;
  const bf16x8 a_h0 = *(const bf16x8*)(ah);
  const bf16x8 a_h1 = *(const bf16x8*)(ah + 32);
  const bf16x8 a_l0 = *(const bf16x8*)(al);
  const bf16x8 a_l1 = *(const bf16x8*)(al + 32);

  const int r     = lane;                         // scan row
  const int nself = rb * 64 + r;                  // self col (within batch)
  unsigned D[16];
#pragma unroll
  for (int i = 0; i < 16; ++i) D[i] = SENTKEY;
  float thrf = 1e30f;
  int cnt = 0;

  auto phase = [&](int p, f32x4 (&out)[4]) {
    const int m0 = c0 + p * 64;
#pragma unroll
    for (int ct = 0; ct < 4; ++ct) {
      const int col = m0 + ct * 16 + l15;
      const __hip_bfloat16* bh = xh + xbase + (size_t)col * 64 + quad * 8;
      const __hip_bfloat16* bl = xl + xbase + (size_t)col * 64 + quad * 8;
      bf16x8 bh0 = *(const bf16x8*)(bh);
      bf16x8 bh1 = *(const bf16x8*)(bh + 32);
      bf16x8 bl0 = *(const bf16x8*)(bl);
      bf16x8 bl1 = *(const bf16x8*)(bl + 32);
      float sv = sq[b * NPTS + col];
      f32x4 acc = { -0.5f * sv, -0.5f * sv, -0.5f * sv, -0.5f * sv };
      acc = __builtin_amdgcn_mfma_f32_16x16x32_bf16(a_h0, bh0, acc, 0, 0, 0);
      acc = __builtin_amdgcn_mfma_f32_16x16x32_bf16(a_h1, bh1, acc, 0, 0, 0);
      acc = __builtin_amdgcn_mfma_f32_16x16x32_bf16(a_h0, bl0, acc, 0, 0, 0);
      acc = __builtin_amdgcn_mfma_f32_16x16x32_bf16(a_h1, bl1, acc, 0, 0, 0);
      acc = __builtin_amdgcn_mfma_f32_16x16x32_bf16(a_l0, bh0, acc, 0, 0, 0);
      acc = __builtin_amdgcn_mfma_f32_16x16x32_bf16(a_l1, bh1, acc, 0, 0, 0);
      out[ct] = acc;
    }
  };

  auto flush = [&]() {
#pragma unroll 1
    for (int g0 = 0; g0 < SLOTS; g0 += 4) {
      if (__ballot(g0 < cnt) == 0ull) break;
      unsigned e0 = bufu[(g0 + 0) * 256 + tid];   // 4 independent reads,
      unsigned e1 = bufu[(g0 + 1) * 256 + tid];   // conflict-free (bank=tid%32)
      unsigned e2 = bufu[(g0 + 2) * 256 + tid];
      unsigned e3 = bufu[(g0 + 3) * 256 + tid];
      if (g0 + 0 < cnt && e0 < D[0]) insertU<16>(D, e0);
      if (g0 + 1 < cnt && e1 < D[0]) insertU<16>(D, e1);
      if (g0 + 2 < cnt && e2 < D[0]) insertU<16>(D, e2);
      if (g0 + 3 < cnt && e3 < D[0]) insertU<16>(D, e3);
    }
    cnt = 0;
    thrf = mono2f(D[0] | 0xFFFu);                 // conservative float mirror
  };

  f32x4 cur[4], nxt[4];
  phase(0, cur);

#pragma unroll 1
  for (int p = 0; p < NPH; ++p) {
    __syncthreads();                              // sc free (prev scan done)
    {
      const int rbase = w * 16 + quad * 4;
#pragma unroll
      for (int ct = 0; ct < 4; ++ct)
#pragma unroll
        for (int i = 0; i < 4; ++i)
          sc[(rbase + i) * SCST + ct * 16 + l15] = -2.f * cur[ct][i];
    }
    if (p + 1 < NPH) phase(p + 1, nxt);           // overlaps barrier + scan
    __syncthreads();                              // sc visible
    const float* srow = sc + r * SCST + w * 16;
    const int    mb   = c0 + p * 64 + w * 16;
#pragma unroll 1
    for (int h = 0; h < 2; ++h) {                 // two 8-col windows
#pragma unroll
      for (int j = 0; j < 8; ++j) {
        float s    = srow[h * 8 + j];
        int   mcol = mb + h * 8 + j;
        bool pass = (s <= thrf) & (mcol != nself);
        if (pass) {
          bufu[cnt * 256 + tid] = (f2mono(s) & 0xFFFFF000u) | (unsigned)mcol;
          cnt++;
        }
      }
      if (__any(cnt >= 4)) flush();
    }
#pragma unroll
    for (int ct = 0; ct < 4; ++ct) cur[ct] = nxt[ct];
  }
  flush();

  // ---- epilogue: merge the 4 wave-lists per row -> top-18 for this quarter
  __syncthreads();
  unsigned* scu = (unsigned*)sc;
#pragma unroll
  for (int i = 0; i < 16; ++i) scu[r * SCST + w * 16 + i] = D[i];
  __syncthreads();
  if (tid < 64) {
    unsigned E[18];
#pragma unroll
    for (int i = 0; i < 18; ++i) E[i] = 0xFFFFFFFFu;
#pragma unroll 1
    for (int j = 0; j < 64; ++j) {
      unsigned u = scu[tid * SCST + j];
      if (u < E[0]) insertU<18>(E, u);
    }
    const size_t base = (size_t)(b * NPTS + rb * 64 + tid) * PROW + (size_t)q * 18;
#pragma unroll
    for (int i = 0; i < 18; ++i) part[base + i] = E[i];
  }
}

// ---------------------------------------------------------------------------
// C: merge 4 quarter-lists (72 entries) -> approx top-20 candidates per row
// ---------------------------------------------------------------------------
__global__ __launch_bounds__(256) void k_merge(const unsigned* __restrict__ part,
                                               unsigned short* __restrict__ cand) {
  const int row = blockIdx.x * 256 + threadIdx.x;   // 0..32767
  unsigned D[20];
#pragma unroll
  for (int i = 0; i < 20; ++i) D[i] = 0xFFFFFFFFu;
  const uint4* pr = (const uint4*)(part + (size_t)row * PROW);
#pragma unroll 2
  for (int i = 0; i < 18; ++i) {                    // 72 u32 = 18 uint4
    uint4 v = pr[i];
    if (v.x < D[0]) insertU<20>(D, v.x);
    if (v.y < D[0]) insertU<20>(D, v.y);
    if (v.z < D[0]) insertU<20>(D, v.z);
    if (v.w < D[0]) insertU<20>(D, v.w);
  }
#pragma unroll
  for (int i = 0; i < 20; ++i) cand[(size_t)row * 20 + i] = (unsigned short)(D[i] & 0xFFFu);
}

// ---------------------------------------------------------------------------
// D: lane-parallel exact fp32 rerank. Lane = (row, candidate): 32-lane group
// per row, lanes 0..19 active. Rank via width-32 shfl compares -> knn[16].
// ---------------------------------------------------------------------------
__global__ __launch_bounds__(256) void k_rerank(const float* __restrict__ xt,
                                                const float* __restrict__ sq,
                                                const unsigned short* __restrict__ cand,
                                                int* __restrict__ knn) {
  const int row = blockIdx.x * 8 + (threadIdx.x >> 5);   // 8 rows per block
  const int c   = threadIdx.x & 31;
  const int b   = row >> 12;
  const int m   = cand[(size_t)row * 20 + (c < 20 ? c : 0)];
  const float4* cr = (const float4*)(xt + (size_t)row * 64);
  const float4* mr = (const float4*)(xt + ((size_t)(b << 12) + m) * 64);
  float d = 0.f;
#pragma unroll
  for (int j = 0; j < 16; ++j) {
    float4 a = cr[j], v = mr[j];
    d = fmaf(a.x, v.x, d); d = fmaf(a.y, v.y, d);
    d = fmaf(a.z, v.z, d); d = fmaf(a.w, v.w, d);
  }
  const float key = sq[(b << 12) + m] - 2.f * d;    // exact fp32 rank key
  int rk = 0;
#pragma unroll
  for (int j = 0; j < 20; ++j) {
    float kj = __shfl(key, j, 32);
    int   mj = __shfl(m, j, 32);
    rk += (kj < key) || ((kj == key) && (mj < m));
  }
  if (c < 20 && rk < 16) knn[(size_t)row * 16 + rk] = m;
}

// ---------------------------------------------------------------------------
// E: P[n][o] = W1[o]·xt[n] ;  Q[n][o] = (W2-W1)[o]·xt[n] + b1[o] + b2[o]
// ---------------------------------------------------------------------------
__global__ __launch_bounds__(256, 4) void k_pq(const float* __restrict__ xt,
                                               const float* __restrict__ W1,
                                               const float* __restrict__ b1,
                                               const float* __restrict__ W2,
                                               const float* __restrict__ b2,
                                               float* __restrict__ P,
                                               float* __restrict__ Q) {
  const int gn = blockIdx.x * 256 + threadIdx.x;
  const int o0 = blockIdx.y * 16;
  float cen[64];
  {
    const float4* s4 = (const float4*)(xt + (size_t)gn * 64);
    float4* c4 = (float4*)cen;
#pragma unroll
    for (int i = 0; i < 16; ++i) c4[i] = s4[i];
  }
#pragma unroll 1
  for (int oi = 0; oi < 16; ++oi) {
    const int o = o0 + oi;
    float p = 0.f, q2 = 0.f;
#pragma unroll
    for (int c = 0; c < 64; ++c) {
      p  = fmaf(W1[o * 64 + c], cen[c], p);
      q2 = fmaf(W2[o * 64 + c], cen[c], q2);
    }
    P[(size_t)gn * 64 + o] = p;
    Q[(size_t)gn * 64 + o] = q2 - p + b1[o] + b2[o];
  }
}

// ---------------------------------------------------------------------------
// F: y[n][o] = relu(max_k (Q[n][o] + P[knn[n][k]][o]))
// ---------------------------------------------------------------------------
__global__ __launch_bounds__(256) void k_out(const float* __restrict__ P,
                                             const float* __restrict__ Q,
                                             const int* __restrict__ knn,
                                             float* __restrict__ out) {
  __shared__ float tile[64][65];
  const int b    = blockIdx.y;
  const int n0   = blockIdx.x * 64;
  const int wave = threadIdx.x >> 6;
  const int lane = threadIdx.x & 63;
  for (int i = 0; i < 16; ++i) {
    const int nl = wave * 16 + i;
    const int gn = b * NPTS + n0 + nl;
    float acc = -1e30f;
    const float qv = Q[(size_t)gn * 64 + lane];
    const int* id = knn + (size_t)gn * 16;
#pragma unroll
    for (int k = 0; k < 16; ++k) {
      int m = id[k];
      float p = P[((size_t)b * NPTS + m) * 64 + lane];
      acc = fmaxf(acc, qv + p);
    }
    tile[nl][lane] = fmaxf(acc, 0.f);
  }
  __syncthreads();
#pragma unroll
  for (int i = 0; i < 16; ++i) {
    const int o = i * 4 + wave;
    out[((size_t)b * 64 + o) * NPTS + n0 + lane] = tile[lane][o];
  }
}

// ---------------------------------------------------------------------------
extern "C" void kernel_launch(void* const* d_in, const int* in_sizes, int n_in,
                              void* d_out, int out_size, void* d_ws, size_t ws_size,
                              hipStream_t stream) {
  const float* x  = (const float*)d_in[0];
  const float* W1 = (const float*)d_in[1];
  const float* b1 = (const float*)d_in[2];
  const float* W2 = (const float*)d_in[3];
  const float* b2 = (const float*)d_in[4];
  float* out = (float*)d_out;

  // workspace ~30 MB (<= proven 43.7 MB)
  float* ws = (float*)d_ws;
  const size_t NPT_ALL = (size_t)NB * NPTS;                 // 32768
  float*          XT   = ws;                                // 8.39 MB
  float*          SQ   = XT + NPT_ALL * 64;                 // 0.13 MB
  __hip_bfloat16* XH   = (__hip_bfloat16*)(SQ + NPT_ALL);   // 4.19 MB
  __hip_bfloat16* XL   = XH + NPT_ALL * 64;                 // 4.19 MB
  unsigned*       PART = (unsigned*)(XL + NPT_ALL * 64);    // 9.44 MB
  unsigned short* CAND = (unsigned short*)(PART + NPT_ALL * PROW); // 1.31 MB
  int*            KNN  = (int*)(CAND + NPT_ALL * 20);       // 2.10 MB
  float*          Pm   = (float*)PART;   // overlay: PART dead after merge
  float*          Qm   = (float*)XH;     // overlay: XH/XL dead after gram

  k_prep  <<<dim3(NPTS / 64, NB), 256, 0, stream>>>(x, XT, XH, XL, SQ);
  k_gram  <<<dim3(64, NQ, NB), 256, 0, stream>>>(XH, XL, SQ, PART);
  k_merge <<<dim3(NPT_ALL / 256), 256, 0, stream>>>(PART, CAND);
  k_rerank<<<dim3(NPT_ALL / 8), 256, 0, stream>>>(XT, SQ, CAND, KNN);
  k_pq    <<<dim3(NPT_ALL / 256, 4), 256, 0, stream>>>(XT, W1, b1, W2, b2, Pm, Qm);
  k_out   <<<dim3(NPTS / 64, NB), 256, 0, stream>>>(Pm, Qm, KNN, out);
}

// Round 8
// 467.056 us; speedup vs baseline: 1.5374x; 1.0990x over previous
//
#include <hip/hip_runtime.h>
#include <hip/hip_bf16.h>
#include <cstdint>

#define NB    8
#define NPTS  4096
#define NQ    4              // col-quarters (blockIdx.y)
#define NT    64             // cand tiles per quarter (1024/16)
#define PROW  64             // part row stride in u32 (4 quarters x 16)
#define SENT  0xFF000000u    // sentinel key (mono2f -> ~1.7e38, finite)

typedef __attribute__((ext_vector_type(8))) short bf16x8;
typedef __attribute__((ext_vector_type(4))) float f32x4;

// monotone float<->uint maps (ascending u <=> ascending f)
__device__ __forceinline__ unsigned f2mono(float f) {
  unsigned b = __float_as_uint(f);
  return b ^ (((int)b < 0) ? 0xFFFFFFFFu : 0x80000000u);
}
__device__ __forceinline__ float mono2f(unsigned u) {
  return __uint_as_float(u ^ (((int)u < 0) ? 0x80000000u : 0xFFFFFFFFu));
}

// insert u into sorted-descending top-N (D[0]=worst); caller checks u<D[0].
template <int N>
__device__ __forceinline__ void insertU(unsigned (&D)[N], unsigned u) {
  bool c[N];
#pragma unroll
  for (int i = 0; i < N; ++i) c[i] = (D[i] > u);
#pragma unroll
  for (int i = 0; i < N; ++i) {
    bool     cn = (i < N - 1) ? c[i + 1] : false;
    unsigned dn = (i < N - 1) ? D[i + 1] : 0u;
    D[i] = cn ? dn : (c[i] ? u : D[i]);
  }
}

// ---------------------------------------------------------------------------
// A: x [B,C,N] -> XT fp32 [B,N,64], XH/XL bf16 split [B,N,64], sq[b,n]
// ---------------------------------------------------------------------------
__global__ __launch_bounds__(256) void k_prep(const float* __restrict__ x,
                                              float* __restrict__ xt,
                                              __hip_bfloat16* __restrict__ xh,
                                              __hip_bfloat16* __restrict__ xl,
                                              float* __restrict__ sq) {
  __shared__ float tile[64][65];
  const int b  = blockIdx.y;
  const int n0 = blockIdx.x * 64;
  const int t  = threadIdx.x;
#pragma unroll
  for (int i = 0; i < 16; ++i) {
    int lin = i * 256 + t;
    int c = lin >> 6, j = lin & 63;
    tile[j][c] = x[(size_t)b * 64 * NPTS + (size_t)c * NPTS + n0 + j];
  }
  __syncthreads();
#pragma unroll
  for (int i = 0; i < 16; ++i) {
    int lin = i * 256 + t;
    int j = lin >> 6, c = lin & 63;
    float v = tile[j][c];
    size_t o = ((size_t)b * NPTS + n0 + j) * 64 + c;
    xt[o] = v;
    __hip_bfloat16 h = __float2bfloat16(v);
    xh[o] = h;
    xl[o] = __float2bfloat16(v - __bfloat162float(h));
  }
  if (t < 64) {
    float s = 0.f;
#pragma unroll
    for (int c = 0; c < 64; ++c) { float v = tile[t][c]; s = fmaf(v, v, s); }
    sq[b * NPTS + t + n0] = s;
  }
}

// ---------------------------------------------------------------------------
// B: barrier-free transposed-MFMA KNN. Wave = 16 rows; A-operand = candidate
// tile (16 cands), B-operand = the wave's rows -> lane (quad,l15) receives
// scores of cands quad*4+{0..3} for row l15. Per-lane sorted top-16 with
// slot-major LDS defer buffer + bitonic batch merge; cross-quad shfl merge.
// No __syncthreads anywhere.
// ---------------------------------------------------------------------------
struct Frag { bf16x8 h0, h1, l0, l1; float4 sv; };

__global__ __launch_bounds__(256, 4) void k_knn(const __hip_bfloat16* __restrict__ xh,
                                                const __hip_bfloat16* __restrict__ xl,
                                                const float* __restrict__ sq,
                                                unsigned* __restrict__ part) {
  __shared__ unsigned bufu[16 * 256];             // 16 KB, slot-major

  const int tid  = threadIdx.x;
  const int w    = tid >> 6;                      // wave -> 16-row tile
  const int lane = tid & 63;
  const int quad = lane >> 4, l15 = lane & 15;
  const int rb   = blockIdx.x;                    // 0..63 row-block (64 rows)
  const int q    = blockIdx.y;                    // 0..3 col-quarter
  const int b    = blockIdx.z;                    // 0..7
  const size_t xbase = (size_t)b * NPTS * 64;
  const int c0   = q * 1024;
  const int nrow = rb * 64 + w * 16 + l15;        // this lane's row

  // persistent B-operand fragments: the wave's rows
  const __hip_bfloat16* ph = xh + xbase + (size_t)nrow * 64 + quad * 8;
  const __hip_bfloat16* pl = xl + xbase + (size_t)nrow * 64 + quad * 8;
  const bf16x8 rh0 = *(const bf16x8*)(ph);
  const bf16x8 rh1 = *(const bf16x8*)(ph + 32);
  const bf16x8 rl0 = *(const bf16x8*)(pl);
  const bf16x8 rl1 = *(const bf16x8*)(pl + 32);

  unsigned D[16];                                 // sorted ascending, D[15]=worst
#pragma unroll
  for (int i = 0; i < 16; ++i) D[i] = SENT;
  float thrf = mono2f(SENT | 0xFFFu);
  int cnt = 0;

  auto ldfrag = [&](int t) -> Frag {
    Frag f;
    const __hip_bfloat16* ah = xh + xbase + (size_t)(c0 + t * 16 + l15) * 64 + quad * 8;
    const __hip_bfloat16* al = xl + xbase + (size_t)(c0 + t * 16 + l15) * 64 + quad * 8;
    f.h0 = *(const bf16x8*)(ah);
    f.h1 = *(const bf16x8*)(ah + 32);
    f.l0 = *(const bf16x8*)(al);
    f.l1 = *(const bf16x8*)(al + 32);
    f.sv = *(const float4*)(sq + b * NPTS + c0 + t * 16 + quad * 4);
    return f;
  };

  auto flush = [&]() {
    unsigned E[16];
#pragma unroll
    for (int j = 0; j < 16; ++j) E[j] = bufu[j * 256 + tid];   // conflict-free
#pragma unroll
    for (int j = 0; j < 16; ++j) E[j] = (j < cnt) ? E[j] : 0xFFFFFFFFu;
    // bitonic full sort ascending (n=16)
#pragma unroll
    for (int k = 2; k <= 16; k <<= 1)
#pragma unroll
      for (int j = k >> 1; j > 0; j >>= 1)
#pragma unroll
        for (int i = 0; i < 16; ++i) {
          int l = i ^ j;
          if (l > i) {
            unsigned lo = min(E[i], E[l]), hi = max(E[i], E[l]);
            bool up = ((i & k) == 0);
            E[i] = up ? lo : hi;
            E[l] = up ? hi : lo;
          }
        }
    // keep 16 smallest of D ∪ E: bitonic combine + clean
    unsigned T[16];
#pragma unroll
    for (int i = 0; i < 16; ++i) T[i] = min(D[i], E[15 - i]);
#pragma unroll
    for (int j = 8; j > 0; j >>= 1)
#pragma unroll
      for (int i = 0; i < 16; ++i) {
        int l = i ^ j;
        if (l > i) {
          unsigned lo = min(T[i], T[l]);
          T[l] = max(T[i], T[l]);
          T[i] = lo;
        }
      }
#pragma unroll
    for (int i = 0; i < 16; ++i) D[i] = T[i];
    cnt = 0;
    thrf = mono2f(D[15] | 0xFFFu);
  };

  Frag fc = ldfrag(0);
#pragma unroll 1
  for (int t = 0; t < NT; ++t) {
    Frag fn;
    if (t + 1 < NT) fn = ldfrag(t + 1);           // prefetch next tile
    f32x4 a1 = { -0.5f * fc.sv.x, -0.5f * fc.sv.y, -0.5f * fc.sv.z, -0.5f * fc.sv.w };
    f32x4 a2 = { 0.f, 0.f, 0.f, 0.f };
    a1 = __builtin_amdgcn_mfma_f32_16x16x32_bf16(fc.h0, rh0, a1, 0, 0, 0);
    a2 = __builtin_amdgcn_mfma_f32_16x16x32_bf16(fc.h0, rl0, a2, 0, 0, 0);
    a1 = __builtin_amdgcn_mfma_f32_16x16x32_bf16(fc.h1, rh1, a1, 0, 0, 0);
    a2 = __builtin_amdgcn_mfma_f32_16x16x32_bf16(fc.h1, rl1, a2, 0, 0, 0);
    a2 = __builtin_amdgcn_mfma_f32_16x16x32_bf16(fc.l0, rh0, a2, 0, 0, 0);
    a2 = __builtin_amdgcn_mfma_f32_16x16x32_bf16(fc.l1, rh1, a2, 0, 0, 0);
    const int cbase = c0 + t * 16 + quad * 4;
#pragma unroll
    for (int i = 0; i < 4; ++i) {
      float s = -2.f * (a1[i] + a2[i]);           // rank key: sq[m] - 2*dot
      int   m = cbase + i;
      bool pass = (s <= thrf) & (m != nrow);
      if (pass) {
        bufu[cnt * 256 + tid] = (f2mono(s) & 0xFFFFF000u) | (unsigned)m;
        cnt++;
      }
    }
    if (__any(cnt >= 13)) flush();                // +4/tile max -> never >16
    fc = fn;
  }
  flush();

  // cross-quad merge: 2 rounds of shfl_xor bitonic top-16 merging
#pragma unroll
  for (int rd = 0; rd < 2; ++rd) {
    const int dx = (rd == 0) ? 16 : 32;
    unsigned Bx[16], T[16];
#pragma unroll
    for (int i = 0; i < 16; ++i) Bx[i] = (unsigned)__shfl_xor((int)D[i], dx);
#pragma unroll
    for (int i = 0; i < 16; ++i) T[i] = min(D[i], Bx[15 - i]);
#pragma unroll
    for (int j = 8; j > 0; j >>= 1)
#pragma unroll
      for (int i = 0; i < 16; ++i) {
        int l = i ^ j;
        if (l > i) {
          unsigned lo = min(T[i], T[l]);
          T[l] = max(T[i], T[l]);
          T[i] = lo;
        }
      }
#pragma unroll
    for (int i = 0; i < 16; ++i) D[i] = T[i];
  }
  if (quad == 0) {
    const size_t base = (size_t)(b * NPTS + nrow) * PROW + (size_t)q * 16;
#pragma unroll
    for (int i = 0; i < 16; ++i) part[base + i] = D[i];
  }
}

// ---------------------------------------------------------------------------
// C: merge 4 quarter-lists (64 entries) -> approx top-20 candidates per row
// ---------------------------------------------------------------------------
__global__ __launch_bounds__(256) void k_merge(const unsigned* __restrict__ part,
                                               unsigned short* __restrict__ cand) {
  const int row = blockIdx.x * 256 + threadIdx.x;   // 0..32767
  unsigned D[20];
#pragma unroll
  for (int i = 0; i < 20; ++i) D[i] = 0xFFFFFFFFu;
  const uint4* pr = (const uint4*)(part + (size_t)row * PROW);
#pragma unroll 2
  for (int i = 0; i < 16; ++i) {                    // 64 u32 = 16 uint4
    uint4 v = pr[i];
    if (v.x < D[0]) insertU<20>(D, v.x);
    if (v.y < D[0]) insertU<20>(D, v.y);
    if (v.z < D[0]) insertU<20>(D, v.z);
    if (v.w < D[0]) insertU<20>(D, v.w);
  }
#pragma unroll
  for (int i = 0; i < 20; ++i) cand[(size_t)row * 20 + i] = (unsigned short)(D[i] & 0xFFFu);
}

// ---------------------------------------------------------------------------
// D: lane-parallel exact fp32 rerank. Lane = (row, candidate): 32-lane group
// per row, lanes 0..19 active. Rank via width-32 shfl compares -> knn[16].
// ---------------------------------------------------------------------------
__global__ __launch_bounds__(256) void k_rerank(const float* __restrict__ xt,
                                                const float* __restrict__ sq,
                                                const unsigned short* __restrict__ cand,
                                                int* __restrict__ knn) {
  const int row = blockIdx.x * 8 + (threadIdx.x >> 5);   // 8 rows per block
  const int c   = threadIdx.x & 31;
  const int b   = row >> 12;
  const int m   = cand[(size_t)row * 20 + (c < 20 ? c : 0)];
  const float4* cr = (const float4*)(xt + (size_t)row * 64);
  const float4* mr = (const float4*)(xt + ((size_t)(b << 12) + m) * 64);
  float d = 0.f;
#pragma unroll
  for (int j = 0; j < 16; ++j) {
    float4 a = cr[j], v = mr[j];
    d = fmaf(a.x, v.x, d); d = fmaf(a.y, v.y, d);
    d = fmaf(a.z, v.z, d); d = fmaf(a.w, v.w, d);
  }
  const float key = sq[(b << 12) + m] - 2.f * d;    // exact fp32 rank key
  int rk = 0;
#pragma unroll
  for (int j = 0; j < 20; ++j) {
    float kj = __shfl(key, j, 32);
    int   mj = __shfl(m, j, 32);
    rk += (kj < key) || ((kj == key) && (mj < m));
  }
  if (c < 20 && rk < 16) knn[(size_t)row * 16 + rk] = m;
}

// ---------------------------------------------------------------------------
// E: P[n][o] = W1[o]·xt[n] ;  Q[n][o] = (W2-W1)[o]·xt[n] + b1[o] + b2[o]
// ---------------------------------------------------------------------------
__global__ __launch_bounds__(256, 4) void k_pq(const float* __restrict__ xt,
                                               const float* __restrict__ W1,
                                               const float* __restrict__ b1,
                                               const float* __restrict__ W2,
                                               const float* __restrict__ b2,
                                               float* __restrict__ P,
                                               float* __restrict__ Q) {
  const int gn = blockIdx.x * 256 + threadIdx.x;
  const int o0 = blockIdx.y * 16;
  float cen[64];
  {
    const float4* s4 = (const float4*)(xt + (size_t)gn * 64);
    float4* c4 = (float4*)cen;
#pragma unroll
    for (int i = 0; i < 16; ++i) c4[i] = s4[i];
  }
#pragma unroll 1
  for (int oi = 0; oi < 16; ++oi) {
    const int o = o0 + oi;
    float p = 0.f, q2 = 0.f;
#pragma unroll
    for (int c = 0; c < 64; ++c) {
      p  = fmaf(W1[o * 64 + c], cen[c], p);
      q2 = fmaf(W2[o * 64 + c], cen[c], q2);
    }
    P[(size_t)gn * 64 + o] = p;
    Q[(size_t)gn * 64 + o] = q2 - p + b1[o] + b2[o];
  }
}

// ---------------------------------------------------------------------------
// F: y[n][o] = relu(max_k (Q[n][o] + P[knn[n][k]][o]))
// ---------------------------------------------------------------------------
__global__ __launch_bounds__(256) void k_out(const float* __restrict__ P,
                                             const float* __restrict__ Q,
                                             const int* __restrict__ knn,
                                             float* __restrict__ out) {
  __shared__ float tile[64][65];
  const int b    = blockIdx.y;
  const int n0   = blockIdx.x * 64;
  const int wave = threadIdx.x >> 6;
  const int lane = threadIdx.x & 63;
  for (int i = 0; i < 16; ++i) {
    const int nl = wave * 16 + i;
    const int gn = b * NPTS + n0 + nl;
    float acc = -1e30f;
    const float qv = Q[(size_t)gn * 64 + lane];
    const int* id = knn + (size_t)gn * 16;
#pragma unroll
    for (int k = 0; k < 16; ++k) {
      int m = id[k];
      float p = P[((size_t)b * NPTS + m) * 64 + lane];
      acc = fmaxf(acc, qv + p);
    }
    tile[nl][lane] = fmaxf(acc, 0.f);
  }
  __syncthreads();
#pragma unroll
  for (int i = 0; i < 16; ++i) {
    const int o = i * 4 + wave;
    out[((size_t)b * 64 + o) * NPTS + n0 + lane] = tile[lane][o];
  }
}

// ---------------------------------------------------------------------------
extern "C" void kernel_launch(void* const* d_in, const int* in_sizes, int n_in,
                              void* d_out, int out_size, void* d_ws, size_t ws_size,
                              hipStream_t stream) {
  const float* x  = (const float*)d_in[0];
  const float* W1 = (const float*)d_in[1];
  const float* b1 = (const float*)d_in[2];
  const float* W2 = (const float*)d_in[3];
  const float* b2 = (const float*)d_in[4];
  float* out = (float*)d_out;

  // workspace ~28.8 MB (<= ~35 MB proven in earlier rounds)
  float* ws = (float*)d_ws;
  const size_t NPT_ALL = (size_t)NB * NPTS;                 // 32768
  float*          XT   = ws;                                // 8.39 MB
  float*          SQ   = XT + NPT_ALL * 64;                 // 0.13 MB
  __hip_bfloat16* XH   = (__hip_bfloat16*)(SQ + NPT_ALL);   // 4.19 MB
  __hip_bfloat16* XL   = XH + NPT_ALL * 64;                 // 4.19 MB
  unsigned*       PART = (unsigned*)(XL + NPT_ALL * 64);    // 8.39 MB
  unsigned short* CAND = (unsigned short*)(PART + NPT_ALL * PROW); // 1.31 MB
  int*            KNN  = (int*)(CAND + NPT_ALL * 20);       // 2.10 MB
  float*          Pm   = (float*)PART;   // overlay: PART dead after merge
  float*          Qm   = (float*)XH;     // overlay: XH/XL dead after knn

  k_prep  <<<dim3(NPTS / 64, NB), 256, 0, stream>>>(x, XT, XH, XL, SQ);
  k_knn   <<<dim3(64, NQ, NB), 256, 0, stream>>>(XH, XL, SQ, PART);
  k_merge <<<dim3(NPT_ALL / 256), 256, 0, stream>>>(PART, CAND);
  k_rerank<<<dim3(NPT_ALL / 8), 256, 0, stream>>>(XT, SQ, CAND, KNN);
  k_pq    <<<dim3(NPT_ALL / 256, 4), 256, 0, stream>>>(XT, W1, b1, W2, b2, Pm, Qm);
  k_out   <<<dim3(NPTS / 64, NB), 256, 0, stream>>>(Pm, Qm, KNN, out);
}

// Round 9
// 444.777 us; speedup vs baseline: 1.6144x; 1.0501x over previous
//
#include <hip/hip_runtime.h>
#include <hip/hip_bf16.h>
#include <cstdint>

#define NB    8
#define NPTS  4096
#define NQ    4              // col-quarters (blockIdx.y)
#define NT    64             // cand tiles per quarter (1024/16)
#define PROW  64             // part row stride in u32 (4 quarters x 16)
#define SENT  0xFF000000u    // sentinel key (mono2f -> ~1.7e38, finite)

typedef __attribute__((ext_vector_type(8))) short bf16x8;
typedef __attribute__((ext_vector_type(4))) float f32x4;

// monotone float<->uint maps (ascending u <=> ascending f)
__device__ __forceinline__ unsigned f2mono(float f) {
  unsigned b = __float_as_uint(f);
  return b ^ (((int)b < 0) ? 0xFFFFFFFFu : 0x80000000u);
}
__device__ __forceinline__ float mono2f(unsigned u) {
  return __uint_as_float(u ^ (((int)u < 0) ? 0x80000000u : 0xFFFFFFFFu));
}

// ---------------------------------------------------------------------------
// A: x [B,C,N] -> XT fp32 [B,N,64], XH/XL bf16 split [B,N,64], sq[b,n]
// ---------------------------------------------------------------------------
__global__ __launch_bounds__(256) void k_prep(const float* __restrict__ x,
                                              float* __restrict__ xt,
                                              __hip_bfloat16* __restrict__ xh,
                                              __hip_bfloat16* __restrict__ xl,
                                              float* __restrict__ sq) {
  __shared__ float tile[64][65];
  const int b  = blockIdx.y;
  const int n0 = blockIdx.x * 64;
  const int t  = threadIdx.x;
#pragma unroll
  for (int i = 0; i < 16; ++i) {
    int lin = i * 256 + t;
    int c = lin >> 6, j = lin & 63;
    tile[j][c] = x[(size_t)b * 64 * NPTS + (size_t)c * NPTS + n0 + j];
  }
  __syncthreads();
#pragma unroll
  for (int i = 0; i < 16; ++i) {
    int lin = i * 256 + t;
    int j = lin >> 6, c = lin & 63;
    float v = tile[j][c];
    size_t o = ((size_t)b * NPTS + n0 + j) * 64 + c;
    xt[o] = v;
    __hip_bfloat16 h = __float2bfloat16(v);
    xh[o] = h;
    xl[o] = __float2bfloat16(v - __bfloat162float(h));
  }
  if (t < 64) {
    float s = 0.f;
#pragma unroll
    for (int c = 0; c < 64; ++c) { float v = tile[t][c]; s = fmaf(v, v, s); }
    sq[b * NPTS + t + n0] = s;
  }
}

// ---------------------------------------------------------------------------
// A2: G = [W1 ; W2-W1] bf16-split (GH/GL, 128x64) + BB = b1+b2 (64)
// ---------------------------------------------------------------------------
__global__ __launch_bounds__(256) void k_gsplit(const float* __restrict__ W1,
                                                const float* __restrict__ b1,
                                                const float* __restrict__ W2,
                                                const float* __restrict__ b2,
                                                __hip_bfloat16* __restrict__ gh,
                                                __hip_bfloat16* __restrict__ gl,
                                                float* __restrict__ bb) {
  const int t = threadIdx.x;
#pragma unroll 1
  for (int i = t; i < 128 * 64; i += 256) {
    int o = i >> 6, c = i & 63;
    float g = (o < 64) ? W1[o * 64 + c]
                       : (W2[(o - 64) * 64 + c] - W1[(o - 64) * 64 + c]);
    __hip_bfloat16 h = __float2bfloat16(g);
    gh[i] = h;
    gl[i] = __float2bfloat16(g - __bfloat162float(h));
  }
  if (t < 64) bb[t] = b1[t] + b2[t];
}

// ---------------------------------------------------------------------------
// B: barrier-free transposed-MFMA KNN. Wave = 16 rows; A-operand = candidate
// tile (16 cands), B = the wave's rows -> lane (quad,l15) gets scores of
// cands quad*4+{0..3} for row l15. SIX independent MFMA accumulators (no
// serial chain). Per-lane sorted top-16, slot-major defer buffer + bitonic
// batch merge; cross-quad shfl merge. No __syncthreads.
// ---------------------------------------------------------------------------
struct Frag { bf16x8 h0, h1, l0, l1; float4 sv; };

__global__ __launch_bounds__(256, 4) void k_knn(const __hip_bfloat16* __restrict__ xh,
                                                const __hip_bfloat16* __restrict__ xl,
                                                const float* __restrict__ sq,
                                                unsigned* __restrict__ part) {
  __shared__ unsigned bufu[16 * 256];             // 16 KB, slot-major

  const int tid  = threadIdx.x;
  const int w    = tid >> 6;                      // wave -> 16-row tile
  const int lane = tid & 63;
  const int quad = lane >> 4, l15 = lane & 15;
  const int rb   = blockIdx.x;                    // 0..63 row-block (64 rows)
  const int q    = blockIdx.y;                    // 0..3 col-quarter
  const int b    = blockIdx.z;                    // 0..7
  const size_t xbase = (size_t)b * NPTS * 64;
  const int c0   = q * 1024;
  const int nrow = rb * 64 + w * 16 + l15;        // this lane's row

  // persistent B-operand fragments: the wave's rows
  const __hip_bfloat16* ph = xh + xbase + (size_t)nrow * 64 + quad * 8;
  const __hip_bfloat16* pl = xl + xbase + (size_t)nrow * 64 + quad * 8;
  const bf16x8 rh0 = *(const bf16x8*)(ph);
  const bf16x8 rh1 = *(const bf16x8*)(ph + 32);
  const bf16x8 rl0 = *(const bf16x8*)(pl);
  const bf16x8 rl1 = *(const bf16x8*)(pl + 32);

  unsigned D[16];                                 // sorted ascending, D[15]=worst
#pragma unroll
  for (int i = 0; i < 16; ++i) D[i] = SENT;
  float thrf = mono2f(SENT | 0xFFFu);
  int cnt = 0;

  auto ldfrag = [&](int t) -> Frag {
    Frag f;
    const __hip_bfloat16* ah = xh + xbase + (size_t)(c0 + t * 16 + l15) * 64 + quad * 8;
    const __hip_bfloat16* al = xl + xbase + (size_t)(c0 + t * 16 + l15) * 64 + quad * 8;
    f.h0 = *(const bf16x8*)(ah);
    f.h1 = *(const bf16x8*)(ah + 32);
    f.l0 = *(const bf16x8*)(al);
    f.l1 = *(const bf16x8*)(al + 32);
    f.sv = *(const float4*)(sq + b * NPTS + c0 + t * 16 + quad * 4);
    return f;
  };

  auto flush = [&]() {
    unsigned E[16];
#pragma unroll
    for (int j = 0; j < 16; ++j) E[j] = bufu[j * 256 + tid];   // conflict-free
#pragma unroll
    for (int j = 0; j < 16; ++j) E[j] = (j < cnt) ? E[j] : 0xFFFFFFFFu;
    // bitonic full sort ascending (n=16)
#pragma unroll
    for (int k = 2; k <= 16; k <<= 1)
#pragma unroll
      for (int j = k >> 1; j > 0; j >>= 1)
#pragma unroll
        for (int i = 0; i < 16; ++i) {
          int l = i ^ j;
          if (l > i) {
            unsigned lo = min(E[i], E[l]), hi = max(E[i], E[l]);
            bool up = ((i & k) == 0);
            E[i] = up ? lo : hi;
            E[l] = up ? hi : lo;
          }
        }
    // keep 16 smallest of D ∪ E: bitonic combine + clean
    unsigned T[16];
#pragma unroll
    for (int i = 0; i < 16; ++i) T[i] = min(D[i], E[15 - i]);
#pragma unroll
    for (int j = 8; j > 0; j >>= 1)
#pragma unroll
      for (int i = 0; i < 16; ++i) {
        int l = i ^ j;
        if (l > i) {
          unsigned lo = min(T[i], T[l]);
          T[l] = max(T[i], T[l]);
          T[i] = lo;
        }
      }
#pragma unroll
    for (int i = 0; i < 16; ++i) D[i] = T[i];
    cnt = 0;
    thrf = mono2f(D[15] | 0xFFFu);
  };

  Frag fc = ldfrag(0);
#pragma unroll 1
  for (int t = 0; t < NT; ++t) {
    Frag fn;
    if (t + 1 < NT) fn = ldfrag(t + 1);           // prefetch next tile
    // 6 fully independent MFMA accumulators (no serial chain)
    f32x4 m1 = { -0.5f * fc.sv.x, -0.5f * fc.sv.y, -0.5f * fc.sv.z, -0.5f * fc.sv.w };
    f32x4 m2 = { 0.f, 0.f, 0.f, 0.f };
    f32x4 m3 = m2, m4 = m2, m5 = m2, m6 = m2;
    m1 = __builtin_amdgcn_mfma_f32_16x16x32_bf16(fc.h0, rh0, m1, 0, 0, 0);
    m2 = __builtin_amdgcn_mfma_f32_16x16x32_bf16(fc.h1, rh1, m2, 0, 0, 0);
    m3 = __builtin_amdgcn_mfma_f32_16x16x32_bf16(fc.h0, rl0, m3, 0, 0, 0);
    m4 = __builtin_amdgcn_mfma_f32_16x16x32_bf16(fc.h1, rl1, m4, 0, 0, 0);
    m5 = __builtin_amdgcn_mfma_f32_16x16x32_bf16(fc.l0, rh0, m5, 0, 0, 0);
    m6 = __builtin_amdgcn_mfma_f32_16x16x32_bf16(fc.l1, rh1, m6, 0, 0, 0);
    const int cbase = c0 + t * 16 + quad * 4;
#pragma unroll
    for (int i = 0; i < 4; ++i) {
      float s = -2.f * (((m1[i] + m2[i]) + (m3[i] + m4[i])) + (m5[i] + m6[i]));
      int   m = cbase + i;
      bool pass = (s <= thrf) & (m != nrow);
      if (pass) {
        bufu[cnt * 256 + tid] = (f2mono(s) & 0xFFFFF000u) | (unsigned)m;
        cnt++;
      }
    }
    if (__any(cnt >= 13)) flush();                // +4/tile max -> never >16
    if (t + 1 < NT) fc = fn;
  }
  flush();

  // cross-quad merge: 2 rounds of shfl_xor bitonic top-16 merging
#pragma unroll
  for (int rd = 0; rd < 2; ++rd) {
    const int dx = (rd == 0) ? 16 : 32;
    unsigned Bx[16], T[16];
#pragma unroll
    for (int i = 0; i < 16; ++i) Bx[i] = (unsigned)__shfl_xor((int)D[i], dx);
#pragma unroll
    for (int i = 0; i < 16; ++i) T[i] = min(D[i], Bx[15 - i]);
#pragma unroll
    for (int j = 8; j > 0; j >>= 1)
#pragma unroll
      for (int i = 0; i < 16; ++i) {
        int l = i ^ j;
        if (l > i) {
          unsigned lo = min(T[i], T[l]);
          T[l] = max(T[i], T[l]);
          T[i] = lo;
        }
      }
#pragma unroll
    for (int i = 0; i < 16; ++i) D[i] = T[i];
  }
  if (quad == 0) {
    const size_t base = (size_t)(b * NPTS + nrow) * PROW + (size_t)q * 16;
#pragma unroll
    for (int i = 0; i < 16; ++i) part[base + i] = D[i];
  }
}

// ---------------------------------------------------------------------------
// C: lane-parallel merge. Part row = 64 globally-distinct packed keys (cols
// are quarter-disjoint). Wave per row; rank = #keys smaller; rank<20 writes.
// ---------------------------------------------------------------------------
__global__ __launch_bounds__(256) void k_merge(const unsigned* __restrict__ part,
                                               unsigned short* __restrict__ cand) {
  const int row  = blockIdx.x * 4 + (threadIdx.x >> 6);
  const int lane = threadIdx.x & 63;
  const unsigned val = part[(size_t)row * PROW + lane];
  int rk = 0;
#pragma unroll
  for (int j = 0; j < 64; ++j) {
    unsigned vj = (unsigned)__shfl((int)val, j);
    rk += (vj < val);
  }
  if (rk < 20) cand[(size_t)row * 20 + rk] = (unsigned short)(val & 0xFFFu);
}

// ---------------------------------------------------------------------------
// D: lane-parallel exact fp32 rerank. Lane = (row, candidate): 32-lane group
// per row, lanes 0..19 active. Rank via width-32 shfl compares -> knn[16].
// ---------------------------------------------------------------------------
__global__ __launch_bounds__(256) void k_rerank(const float* __restrict__ xt,
                                                const float* __restrict__ sq,
                                                const unsigned short* __restrict__ cand,
                                                int* __restrict__ knn) {
  const int row = blockIdx.x * 8 + (threadIdx.x >> 5);   // 8 rows per block
  const int c   = threadIdx.x & 31;
  const int b   = row >> 12;
  const int m   = cand[(size_t)row * 20 + (c < 20 ? c : 0)];
  const float4* cr = (const float4*)(xt + (size_t)row * 64);
  const float4* mr = (const float4*)(xt + ((size_t)(b << 12) + m) * 64);
  float d = 0.f;
#pragma unroll
  for (int j = 0; j < 16; ++j) {
    float4 a = cr[j], v = mr[j];
    d = fmaf(a.x, v.x, d); d = fmaf(a.y, v.y, d);
    d = fmaf(a.z, v.z, d); d = fmaf(a.w, v.w, d);
  }
  const float key = sq[(b << 12) + m] - 2.f * d;    // exact fp32 rank key
  int rk = 0;
#pragma unroll
  for (int j = 0; j < 20; ++j) {
    float kj = __shfl(key, j, 32);
    int   mj = __shfl(m, j, 32);
    rk += (kj < key) || ((kj == key) && (mj < m));
  }
  if (c < 20 && rk < 16) knn[(size_t)row * 16 + rk] = m;
}

// ---------------------------------------------------------------------------
// E: MFMA P/Q GEMM. P = X·W1^T ; Q = X·(W2-W1)^T + (b1+b2), via G=[W1;W2-W1]
// bf16-split (hh+hl+lh). Wave = 16 rows x 128 outs (8 tiles, 48 MFMAs).
// ---------------------------------------------------------------------------
__global__ __launch_bounds__(256) void k_pq(const __hip_bfloat16* __restrict__ xh,
                                            const __hip_bfloat16* __restrict__ xl,
                                            const __hip_bfloat16* __restrict__ gh,
                                            const __hip_bfloat16* __restrict__ gl,
                                            const float* __restrict__ bb,
                                            float* __restrict__ P,
                                            float* __restrict__ Q) {
  const int tid  = threadIdx.x;
  const int w    = tid >> 6;
  const int lane = tid & 63;
  const int quad = lane >> 4, l15 = lane & 15;
  const int row0 = blockIdx.x * 64 + w * 16;

  const __hip_bfloat16* pa = xh + (size_t)(row0 + l15) * 64 + quad * 8;
  const __hip_bfloat16* pb = xl + (size_t)(row0 + l15) * 64 + quad * 8;
  const bf16x8 ah0 = *(const bf16x8*)(pa);
  const bf16x8 ah1 = *(const bf16x8*)(pa + 32);
  const bf16x8 al0 = *(const bf16x8*)(pb);
  const bf16x8 al1 = *(const bf16x8*)(pb + 32);

#pragma unroll
  for (int ct = 0; ct < 8; ++ct) {
    const __hip_bfloat16* qh = gh + (size_t)(ct * 16 + l15) * 64 + quad * 8;
    const __hip_bfloat16* ql = gl + (size_t)(ct * 16 + l15) * 64 + quad * 8;
    bf16x8 bh0 = *(const bf16x8*)(qh);
    bf16x8 bh1 = *(const bf16x8*)(qh + 32);
    bf16x8 bl0 = *(const bf16x8*)(ql);
    bf16x8 bl1 = *(const bf16x8*)(ql + 32);
    f32x4 m1 = { 0.f, 0.f, 0.f, 0.f };
    f32x4 m2 = m1, m3 = m1, m4 = m1, m5 = m1, m6 = m1;
    m1 = __builtin_amdgcn_mfma_f32_16x16x32_bf16(ah0, bh0, m1, 0, 0, 0);
    m2 = __builtin_amdgcn_mfma_f32_16x16x32_bf16(ah1, bh1, m2, 0, 0, 0);
    m3 = __builtin_amdgcn_mfma_f32_16x16x32_bf16(ah0, bl0, m3, 0, 0, 0);
    m4 = __builtin_amdgcn_mfma_f32_16x16x32_bf16(ah1, bl1, m4, 0, 0, 0);
    m5 = __builtin_amdgcn_mfma_f32_16x16x32_bf16(al0, bh0, m5, 0, 0, 0);
    m6 = __builtin_amdgcn_mfma_f32_16x16x32_bf16(al1, bh1, m6, 0, 0, 0);
    if (ct < 4) {
#pragma unroll
      for (int i = 0; i < 4; ++i) {
        float s = ((m1[i] + m2[i]) + (m3[i] + m4[i])) + (m5[i] + m6[i]);
        P[(size_t)(row0 + quad * 4 + i) * 64 + ct * 16 + l15] = s;
      }
    } else {
      const float bq = bb[(ct - 4) * 16 + l15];
#pragma unroll
      for (int i = 0; i < 4; ++i) {
        float s = ((m1[i] + m2[i]) + (m3[i] + m4[i])) + (m5[i] + m6[i]);
        Q[(size_t)(row0 + quad * 4 + i) * 64 + (ct - 4) * 16 + l15] = s + bq;
      }
    }
  }
}

// ---------------------------------------------------------------------------
// F: y[n][o] = relu(max_k (Q[n][o] + P[knn[n][k]][o]))
// ---------------------------------------------------------------------------
__global__ __launch_bounds__(256) void k_out(const float* __restrict__ P,
                                             const float* __restrict__ Q,
                                             const int* __restrict__ knn,
                                             float* __restrict__ out) {
  __shared__ float tile[64][65];
  const int b    = blockIdx.y;
  const int n0   = blockIdx.x * 64;
  const int wave = threadIdx.x >> 6;
  const int lane = threadIdx.x & 63;
  for (int i = 0; i < 16; ++i) {
    const int nl = wave * 16 + i;
    const int gn = b * NPTS + n0 + nl;
    float acc = -1e30f;
    const float qv = Q[(size_t)gn * 64 + lane];
    const int* id = knn + (size_t)gn * 16;
#pragma unroll
    for (int k = 0; k < 16; ++k) {
      int m = id[k];
      float p = P[((size_t)b * NPTS + m) * 64 + lane];
      acc = fmaxf(acc, qv + p);
    }
    tile[nl][lane] = fmaxf(acc, 0.f);
  }
  __syncthreads();
#pragma unroll
  for (int i = 0; i < 16; ++i) {
    const int o = i * 4 + wave;
    out[((size_t)b * 64 + o) * NPTS + n0 + lane] = tile[lane][o];
  }
}

// ---------------------------------------------------------------------------
extern "C" void kernel_launch(void* const* d_in, const int* in_sizes, int n_in,
                              void* d_out, int out_size, void* d_ws, size_t ws_size,
                              hipStream_t stream) {
  const float* x  = (const float*)d_in[0];
  const float* W1 = (const float*)d_in[1];
  const float* b1 = (const float*)d_in[2];
  const float* W2 = (const float*)d_in[3];
  const float* b2 = (const float*)d_in[4];
  float* out = (float*)d_out;

  // workspace ~28.9 MB (<= ~35 MB proven in earlier rounds)
  float* ws = (float*)d_ws;
  const size_t NPT_ALL = (size_t)NB * NPTS;                 // 32768
  float*          XT   = ws;                                // 8.39 MB
  float*          SQ   = XT + NPT_ALL * 64;                 // 0.13 MB
  __hip_bfloat16* XH   = (__hip_bfloat16*)(SQ + NPT_ALL);   // 4.19 MB
  __hip_bfloat16* XL   = XH + NPT_ALL * 64;                 // 4.19 MB
  unsigned*       PART = (unsigned*)(XL + NPT_ALL * 64);    // 8.39 MB
  unsigned short* CAND = (unsigned short*)(PART + NPT_ALL * PROW); // 1.31 MB
  int*            KNN  = (int*)(CAND + NPT_ALL * 20);       // 2.10 MB
  __hip_bfloat16* GH   = (__hip_bfloat16*)(KNN + NPT_ALL * 16); // 16 KB
  __hip_bfloat16* GL   = GH + 128 * 64;                     // 16 KB
  float*          BB   = (float*)(GL + 128 * 64);           // 256 B
  float*          Pm   = (float*)PART;   // overlay: PART dead after merge
  float*          Qm   = (float*)XH;     // overlay: XH/XL dead after pq reads

  k_prep  <<<dim3(NPTS / 64, NB), 256, 0, stream>>>(x, XT, XH, XL, SQ);
  k_gsplit<<<dim3(1), 256, 0, stream>>>(W1, b1, W2, b2, GH, GL, BB);
  k_knn   <<<dim3(64, NQ, NB), 256, 0, stream>>>(XH, XL, SQ, PART);
  k_merge <<<dim3(NPT_ALL / 4), 256, 0, stream>>>(PART, CAND);
  k_rerank<<<dim3(NPT_ALL / 8), 256, 0, stream>>>(XT, SQ, CAND, KNN);
  k_pq    <<<dim3(NPT_ALL / 64), 256, 0, stream>>>(XH, XL, GH, GL, BB, Pm, Qm);
  k_out   <<<dim3(NPTS / 64, NB), 256, 0, stream>>>(Pm, Qm, KNN, out);
}